// Round 2
// baseline (333.407 us; speedup 1.0000x reference)
//
#include <hip/hip_runtime.h>
#include <hip/hip_bf16.h>
#include <math.h>

// BitLinearAttention on gfx950.
// B=2, S=2048, D=1024, H=16, Hd=64, T=B*S=4096. All GEMMs done as exact-integer
// bf16 MFMA (qint in [-128,127], ternary weights), scales applied in epilogue.

typedef float  f32x4  __attribute__((ext_vector_type(4)));
typedef __bf16 bf16x8 __attribute__((ext_vector_type(8)));
typedef unsigned int u32x4 __attribute__((ext_vector_type(4)));

#define EPSV 1e-5f

__device__ __forceinline__ f32x4 mfma16(bf16x8 a, bf16x8 b, f32x4 c) {
    return __builtin_amdgcn_mfma_f32_16x16x32_bf16(a, b, c, 0, 0, 0);
}

__device__ __forceinline__ void gload16(const void* g, void* lds) {
    __builtin_amdgcn_global_load_lds((const __attribute__((address_space(1))) unsigned int*)g,
                                     (__attribute__((address_space(3))) unsigned int*)lds, 16, 0, 0);
}

// ---------------- weight |.| sum (fp64 accumulate) ----------------
__global__ __launch_bounds__(256) void k_wsum(const float* __restrict__ w0, const float* __restrict__ w1,
                                              const float* __restrict__ w2, const float* __restrict__ w3,
                                              double* __restrict__ wsum) {
    int w = blockIdx.x >> 6, chunk = blockIdx.x & 63, tid = threadIdx.x;
    const float* W = (w == 0) ? w0 : (w == 1) ? w1 : (w == 2) ? w2 : w3;
    const float* base = W + (size_t)chunk * 16384;
    float s = 0.f;
#pragma unroll
    for (int i = 0; i < 16; i++) {
        f32x4 v = *(const f32x4*)(base + i * 1024 + tid * 4);
        s += fabsf(v.x) + fabsf(v.y) + fabsf(v.z) + fabsf(v.w);
    }
#pragma unroll
    for (int off = 1; off < 64; off <<= 1) s += __shfl_xor(s, off);
    __shared__ float red[4];
    if ((tid & 63) == 0) red[tid >> 6] = s;
    __syncthreads();
    if (tid == 0) {
        double t = (double)red[0] + (double)red[1] + (double)red[2] + (double)red[3];
        atomicAdd(&wsum[w], t);
    }
}

// ---------------- ternary weight quantization ----------------
__global__ __launch_bounds__(256) void k_wquant(const float* __restrict__ w0, const float* __restrict__ w1,
                                                const float* __restrict__ w2, const float* __restrict__ w3,
                                                const double* __restrict__ wsum,
                                                __bf16* __restrict__ wq, float* __restrict__ wm) {
    int w = blockIdx.y;
    const float* W = (w == 0) ? w0 : (w == 1) ? w1 : (w == 2) ? w2 : w3;
    float mean = (float)(wsum[w] * (1.0 / 1048576.0));
    float ms = fmaxf(mean, EPSV);           // clip(mean, EPS)
    float scale = 1.0f / ms;
    int pos = blockIdx.x * 1024 + threadIdx.x * 4;
    f32x4 v = *(const f32x4*)(W + pos);
    float q0 = fminf(fmaxf(rintf(v.x * scale), -1.f), 1.f);
    float q1 = fminf(fmaxf(rintf(v.y * scale), -1.f), 1.f);
    float q2 = fminf(fmaxf(rintf(v.z * scale), -1.f), 1.f);
    float q3 = fminf(fmaxf(rintf(v.w * scale), -1.f), 1.f);
    unsigned int b0 = __builtin_bit_cast(unsigned short, (__bf16)q0);
    unsigned int b1 = __builtin_bit_cast(unsigned short, (__bf16)q1);
    unsigned int b2 = __builtin_bit_cast(unsigned short, (__bf16)q2);
    unsigned int b3 = __builtin_bit_cast(unsigned short, (__bf16)q3);
    uint2 p; p.x = b0 | (b1 << 16); p.y = b2 | (b3 << 16);
    *(uint2*)(wq + (size_t)w * 1048576 + pos) = p;
    if (blockIdx.x == 0 && threadIdx.x == 0) wm[w] = ms;   // weight multiplier = clip(mean|W|,EPS)
}

// ---------------- per-token int8 absmax act quant (stores integer values as bf16) ----------------
__global__ __launch_bounds__(256) void k_actq(const float* __restrict__ in, __bf16* __restrict__ outq,
                                              float* __restrict__ rs) {
    int t = blockIdx.x, tid = threadIdx.x;
    const float* row = in + (size_t)t * 1024;
    f32x4 v = *(const f32x4*)(row + tid * 4);
    float am = fmaxf(fmaxf(fabsf(v.x), fabsf(v.y)), fmaxf(fabsf(v.z), fabsf(v.w)));
#pragma unroll
    for (int off = 1; off < 64; off <<= 1) am = fmaxf(am, __shfl_xor(am, off));
    __shared__ float red[4];
    if ((tid & 63) == 0) red[tid >> 6] = am;
    __syncthreads();
    am = fmaxf(fmaxf(red[0], red[1]), fmaxf(red[2], red[3]));
    am = fmaxf(am, EPSV);                    // clip(absmax, EPS)
    float scale = 127.0f / am;
    float q0 = fminf(fmaxf(rintf(v.x * scale), -128.f), 127.f);
    float q1 = fminf(fmaxf(rintf(v.y * scale), -128.f), 127.f);
    float q2 = fminf(fmaxf(rintf(v.z * scale), -128.f), 127.f);
    float q3 = fminf(fmaxf(rintf(v.w * scale), -128.f), 127.f);
    unsigned int b0 = __builtin_bit_cast(unsigned short, (__bf16)q0);
    unsigned int b1 = __builtin_bit_cast(unsigned short, (__bf16)q1);
    unsigned int b2 = __builtin_bit_cast(unsigned short, (__bf16)q2);
    unsigned int b3 = __builtin_bit_cast(unsigned short, (__bf16)q3);
    uint2 p; p.x = b0 | (b1 << 16); p.y = b2 | (b3 << 16);
    *(uint2*)(outq + (size_t)t * 1024 + tid * 4) = p;
    if (tid == 0) rs[t] = am / 127.0f;       // 1/scale
}

// ---------------- GEMM: out[m][n] = sum_k X[m][k] * W[n][k], scaled by rs[m]*wm ----------------
// MODE 0: z=0/1 -> bf16 (b,h,s,hd) q/k; z=2 -> swapped operands, writes V^T (bh,hd,s) directly
// MODE 1: write fp32 into d_out (T x 1024)
template <int MODE>
__global__ __launch_bounds__(256) void k_gemm(const __bf16* __restrict__ X, const __bf16* __restrict__ Wb,
                                              const float* __restrict__ rs, const float* __restrict__ wm,
                                              __bf16* __restrict__ o0, __bf16* __restrict__ o1,
                                              __bf16* __restrict__ o2, float* __restrict__ outf) {
    __shared__ __attribute__((aligned(16))) __bf16 As[128 * 32];
    __shared__ __attribute__((aligned(16))) __bf16 Bs[128 * 32];
    int tid = threadIdx.x;
    int wave = tid >> 6, lane = tid & 63, g = lane >> 4, l = lane & 15;
    int m0 = blockIdx.x * 128, n0 = blockIdx.y * 128;
    int z = blockIdx.z;
    const __bf16* W = Wb + (size_t)z * 1048576;
    float wmv = wm[z];
    f32x4 acc[4][4] = {};
    // global_load_lds staging: inst j (0/1), wave w, lane i -> LDS bytes [j*4096 + w*1024 + i*16)
    // => row-major [128][32] row = j*64 + w*16 + (i>>2), col = (i&3)*8
    int srow0 = wave * 16 + (lane >> 2);
    int scol = (lane & 3) * 8;
    const __bf16* Ag = X + (size_t)(m0 + srow0) * 1024 + scol;
    const __bf16* Bg = W + (size_t)(n0 + srow0) * 1024 + scol;
    __bf16* ldsA = As + wave * 512;
    __bf16* ldsB = Bs + wave * 512;
    int wrow = (wave >> 1) * 64, wcol = (wave & 1) * 64;
    bool vswap = (MODE == 0) && (z == 2);
    for (int k0 = 0; k0 < 1024; k0 += 32) {
        __syncthreads();
        gload16(Ag + k0,             ldsA);
        gload16(Ag + 64 * 1024 + k0, ldsA + 2048);
        gload16(Bg + k0,             ldsB);
        gload16(Bg + 64 * 1024 + k0, ldsB + 2048);
        __syncthreads();
        bf16x8 af[4], bfr[4];
#pragma unroll
        for (int i = 0; i < 4; i++) af[i]  = *(const bf16x8*)&As[(wrow + i * 16 + l) * 32 + 8 * g];
#pragma unroll
        for (int i = 0; i < 4; i++) bfr[i] = *(const bf16x8*)&Bs[(wcol + i * 16 + l) * 32 + 8 * g];
        if (vswap) {
#pragma unroll
            for (int mi = 0; mi < 4; mi++)
#pragma unroll
                for (int ni = 0; ni < 4; ni++)
                    acc[mi][ni] = mfma16(bfr[ni], af[mi], acc[mi][ni]);
        } else {
#pragma unroll
            for (int mi = 0; mi < 4; mi++)
#pragma unroll
                for (int ni = 0; ni < 4; ni++)
                    acc[mi][ni] = mfma16(af[mi], bfr[ni], acc[mi][ni]);
        }
    }
    if (vswap) {
        // D row = n-side (W row), col = m-side (X row): write V^T directly
#pragma unroll
        for (int mi = 0; mi < 4; mi++) {
            int m = m0 + wrow + mi * 16 + l;
            float rsm = rs[m] * wmv;
            int b = m >> 11, s2 = m & 2047;
#pragma unroll
            for (int ni = 0; ni < 4; ni++) {
                int nb = n0 + wcol + ni * 16 + 4 * g;
#pragma unroll
                for (int r = 0; r < 4; r++) {
                    int n = nb + r;
                    int h = n >> 6, hd = n & 63;
                    o2[((size_t)(b * 16 + h) * 64 + hd) * 2048 + s2] = (__bf16)(acc[mi][ni][r] * rsm);
                }
            }
        }
        return;
    }
#pragma unroll
    for (int mi = 0; mi < 4; mi++) {
        int mbase = m0 + wrow + mi * 16 + 4 * g;
        f32x4 rv = {rs[mbase], rs[mbase + 1], rs[mbase + 2], rs[mbase + 3]};
#pragma unroll
        for (int ni = 0; ni < 4; ni++) {
            int n = n0 + wcol + ni * 16 + l;
#pragma unroll
            for (int r = 0; r < 4; r++) {
                float v = acc[mi][ni][r] * (rv[r] * wmv);
                if constexpr (MODE == 0) {
                    int m = mbase + r;
                    int b = m >> 11, s2 = m & 2047;
                    int h = n >> 6, hd = n & 63;
                    __bf16* dst = (z == 0) ? o0 : o1;
                    dst[(((size_t)(b * 16 + h)) * 2048 + s2) * 64 + hd] = (__bf16)v;
                } else {
                    outf[(size_t)(mbase + r) * 1024 + n] = v;
                }
            }
        }
    }
}

// ---------------- causal flash attention, barrier-free, one 16-row Q strip pair per wave ----------------
// q/k [bh][s][hd] bf16, vt [bh][hd][s] bf16 -> attn (B,S,D) fp32. K/V read direct from global (L2-resident).
__global__ __launch_bounds__(256) void k_attn(const __bf16* __restrict__ qb, const __bf16* __restrict__ kb,
                                              const __bf16* __restrict__ vt, float* __restrict__ attn) {
    __shared__ __attribute__((aligned(16))) __bf16 Ps[4][1024];   // per-wave 16x64 P, xor-swizzled
    int tid = threadIdx.x, wave = tid >> 6, lane = tid & 63, g = lane >> 4, l = lane & 15;
    int bh = blockIdx.y, bq = bh >> 4, h = bh & 15;
    size_t bhq = (size_t)bh * 2048 * 64;
    char* Pw = (char*)&Ps[wave][0];
    int psw = (l & 7) << 4;
    int p = blockIdx.x * 4 + wave;           // pair index in [0,64): strips p and 127-p
    for (int half = 0; half < 2; half++) {
        int s = half ? (127 - p) : p;
        int q0 = s * 16;
        int qrow = q0 + l;
        bf16x8 aq0 = *(const bf16x8*)(qb + bhq + (size_t)qrow * 64 + 8 * g);
        bf16x8 aq1 = *(const bf16x8*)(qb + bhq + (size_t)qrow * 64 + 32 + 8 * g);
        f32x4 o[4] = {};
        float mreg[4], lsum[4];
#pragma unroll
        for (int r = 0; r < 4; r++) { mreg[r] = -INFINITY; lsum[r] = 0.f; }
        int nt = (s >> 2) + 1;
        for (int ti = 0; ti < nt; ti++) {
            int t0 = ti * 64;
            // S = Q.K^T / 8, K fragments direct from global
            f32x4 sv[4];
#pragma unroll
            for (int nb = 0; nb < 4; nb++) {
                const __bf16* kp = kb + bhq + (size_t)(t0 + nb * 16 + l) * 64;
                bf16x8 bk0 = *(const bf16x8*)(kp + 8 * g);
                bf16x8 bk1 = *(const bf16x8*)(kp + 32 + 8 * g);
                f32x4 a = {};
                a = mfma16(aq0, bk0, a);
                a = mfma16(aq1, bk1, a);
                sv[nb] = a * 0.125f;
            }
            if (ti == nt - 1) {   // causal mask on last tile only
#pragma unroll
                for (int nb = 0; nb < 4; nb++)
#pragma unroll
                    for (int r = 0; r < 4; r++) {
                        int key = t0 + nb * 16 + l;
                        int q = q0 + 4 * g + r;
                        if (key > q) sv[nb][r] = -INFINITY;
                    }
            }
            // online softmax (rows on (g, reg); 16 lanes hold keys)
            float corr[4];
#pragma unroll
            for (int r = 0; r < 4; r++) {
                float v = fmaxf(fmaxf(sv[0][r], sv[1][r]), fmaxf(sv[2][r], sv[3][r]));
                v = fmaxf(v, __shfl_xor(v, 1));
                v = fmaxf(v, __shfl_xor(v, 2));
                v = fmaxf(v, __shfl_xor(v, 4));
                v = fmaxf(v, __shfl_xor(v, 8));
                float mnew = fmaxf(mreg[r], v);
                corr[r] = __expf(mreg[r] - mnew);
                mreg[r] = mnew;
            }
            float ps[4] = {0.f, 0.f, 0.f, 0.f};
#pragma unroll
            for (int nb = 0; nb < 4; nb++)
#pragma unroll
                for (int r = 0; r < 4; r++) {
                    float pe = __expf(sv[nb][r] - mreg[r]);
                    sv[nb][r] = pe;
                    ps[r] += pe;
                }
#pragma unroll
            for (int r = 0; r < 4; r++) {
                float sm = ps[r];
                sm += __shfl_xor(sm, 1);
                sm += __shfl_xor(sm, 2);
                sm += __shfl_xor(sm, 4);
                sm += __shfl_xor(sm, 8);
                lsum[r] = lsum[r] * corr[r] + sm;
#pragma unroll
                for (int hb = 0; hb < 4; hb++) o[hb][r] = o[hb][r] * corr[r];
            }
            // P -> per-wave LDS (bf16), re-read as A fragments (wave-synchronous, no barrier)
#pragma unroll
            for (int nb = 0; nb < 4; nb++)
#pragma unroll
                for (int r = 0; r < 4; r++) {
                    int prow = 4 * g + r;
                    *(__bf16*)(Pw + prow * 128 + ((nb * 32 + 2 * l) ^ ((prow & 7) << 4))) = (__bf16)sv[nb][r];
                }
            bf16x8 pa0 = *(const bf16x8*)(Pw + l * 128 + ((16 * g) ^ psw));
            bf16x8 pa1 = *(const bf16x8*)(Pw + l * 128 + ((64 + 16 * g) ^ psw));
            // PV: V^T fragments direct from global
#pragma unroll
            for (int hb = 0; hb < 4; hb++) {
                const __bf16* vp = vt + bhq + (size_t)(hb * 16 + l) * 2048 + t0;
                bf16x8 v0 = *(const bf16x8*)(vp + 8 * g);
                bf16x8 v1 = *(const bf16x8*)(vp + 32 + 8 * g);
                o[hb] = mfma16(pa0, v0, o[hb]);
                o[hb] = mfma16(pa1, v1, o[hb]);
            }
        }
        // epilogue: write (B,S,D) fp32
#pragma unroll
        for (int r = 0; r < 4; r++) {
            float inv = 1.0f / lsum[r];
            int q = q0 + 4 * g + r;
            float* dst = attn + ((size_t)(bq * 2048 + q)) * 1024 + h * 64 + l;
#pragma unroll
            for (int hb = 0; hb < 4; hb++) dst[hb * 16] = o[hb][r] * inv;
        }
    }
}

extern "C" void kernel_launch(void* const* d_in, const int* in_sizes, int n_in,
                              void* d_out, int out_size, void* d_ws, size_t ws_size,
                              hipStream_t stream) {
    const float* x  = (const float*)d_in[0];
    // d_in[1] = mask: guaranteed causal tril, hardcoded in k_attn
    const float* Wq = (const float*)d_in[2];
    const float* Wk = (const float*)d_in[3];
    const float* Wv = (const float*)d_in[4];
    const float* Wo = (const float*)d_in[5];
    float* out = (float*)d_out;
    char* ws = (char*)d_ws;

    double* wsumd = (double*)(ws + 0);                       // 32 B
    float*  wmv   = (float*)(ws + 256);                      // 16 B
    __bf16* wqall = (__bf16*)(ws + 512);                     // 8 MB (4 x 1M bf16)
    __bf16* xq    = (__bf16*)(ws + 512 + 8388608);           // 8 MB
    float*  rsx   = (float*)(ws + 512 + 16777216);           // 16 KB
    float*  rso   = (float*)(ws + 512 + 16777216 + 16384);   // 16 KB
    char*   big   = ws + 512 + 16777216 + 32768;
    __bf16* qbuf  = (__bf16*)(big);                          // 8 MB
    __bf16* kbuf  = (__bf16*)(big + 8388608);                // 8 MB
    __bf16* oq    = (__bf16*)(big + 16777216);               // 8 MB
    __bf16* vtb   = (__bf16*)(big + 25165824);               // 8 MB (V^T, written by k_gemm z=2)
    float*  attn  = (float*)(big + 33554432);                // 16 MB

    hipMemsetAsync(ws, 0, 512, stream);
    k_wsum<<<dim3(256), 256, 0, stream>>>(Wq, Wk, Wv, Wo, wsumd);
    k_wquant<<<dim3(1024, 4), 256, 0, stream>>>(Wq, Wk, Wv, Wo, wsumd, wqall, wmv);
    k_actq<<<dim3(4096), 256, 0, stream>>>(x, xq, rsx);
    k_gemm<0><<<dim3(32, 8, 3), 256, 0, stream>>>(xq, wqall, rsx, wmv, qbuf, kbuf, vtb, nullptr);
    k_attn<<<dim3(16, 32), 256, 0, stream>>>(qbuf, kbuf, vtb, attn);
    k_actq<<<dim3(4096), 256, 0, stream>>>(attn, oq, rso);
    k_gemm<1><<<dim3(32, 8, 1), 256, 0, stream>>>(oq, wqall + 3 * 1048576, rso, wmv + 3,
                                                  nullptr, nullptr, nullptr, out);
}

// Round 4
// 280.475 us; speedup vs baseline: 1.1887x; 1.1887x over previous
//
#include <hip/hip_runtime.h>
#include <hip/hip_bf16.h>
#include <math.h>

// BitLinearAttention on gfx950.
// B=2, S=2048, D=1024, H=16, Hd=64, T=B*S=4096. All GEMMs done as exact-integer
// bf16 MFMA (qint in [-128,127], ternary weights), scales applied in epilogue.

typedef float  f32x4  __attribute__((ext_vector_type(4)));
typedef __bf16 bf16x8 __attribute__((ext_vector_type(8)));
typedef unsigned int u32x4 __attribute__((ext_vector_type(4)));

#define EPSV 1e-5f

__device__ __forceinline__ f32x4 mfma16(bf16x8 a, bf16x8 b, f32x4 c) {
    return __builtin_amdgcn_mfma_f32_16x16x32_bf16(a, b, c, 0, 0, 0);
}

__device__ __forceinline__ void gload16(const void* g, void* lds) {
    __builtin_amdgcn_global_load_lds((const __attribute__((address_space(1))) unsigned int*)g,
                                     (__attribute__((address_space(3))) unsigned int*)lds, 16, 0, 0);
}

// ---------------- weight |.| sum (fp64 accumulate) ----------------
__global__ __launch_bounds__(256) void k_wsum(const float* __restrict__ w0, const float* __restrict__ w1,
                                              const float* __restrict__ w2, const float* __restrict__ w3,
                                              double* __restrict__ wsum) {
    int w = blockIdx.x >> 6, chunk = blockIdx.x & 63, tid = threadIdx.x;
    const float* W = (w == 0) ? w0 : (w == 1) ? w1 : (w == 2) ? w2 : w3;
    const float* base = W + (size_t)chunk * 16384;
    float s = 0.f;
#pragma unroll
    for (int i = 0; i < 16; i++) {
        f32x4 v = *(const f32x4*)(base + i * 1024 + tid * 4);
        s += fabsf(v.x) + fabsf(v.y) + fabsf(v.z) + fabsf(v.w);
    }
#pragma unroll
    for (int off = 1; off < 64; off <<= 1) s += __shfl_xor(s, off);
    __shared__ float red[4];
    if ((tid & 63) == 0) red[tid >> 6] = s;
    __syncthreads();
    if (tid == 0) {
        double t = (double)red[0] + (double)red[1] + (double)red[2] + (double)red[3];
        atomicAdd(&wsum[w], t);
    }
}

// ---------------- ternary weight quantization ----------------
__global__ __launch_bounds__(256) void k_wquant(const float* __restrict__ w0, const float* __restrict__ w1,
                                                const float* __restrict__ w2, const float* __restrict__ w3,
                                                const double* __restrict__ wsum,
                                                __bf16* __restrict__ wq, float* __restrict__ wm) {
    int w = blockIdx.y;
    const float* W = (w == 0) ? w0 : (w == 1) ? w1 : (w == 2) ? w2 : w3;
    float mean = (float)(wsum[w] * (1.0 / 1048576.0));
    float ms = fmaxf(mean, EPSV);           // clip(mean, EPS)
    float scale = 1.0f / ms;
    int pos = blockIdx.x * 1024 + threadIdx.x * 4;
    f32x4 v = *(const f32x4*)(W + pos);
    float q0 = fminf(fmaxf(rintf(v.x * scale), -1.f), 1.f);
    float q1 = fminf(fmaxf(rintf(v.y * scale), -1.f), 1.f);
    float q2 = fminf(fmaxf(rintf(v.z * scale), -1.f), 1.f);
    float q3 = fminf(fmaxf(rintf(v.w * scale), -1.f), 1.f);
    unsigned int b0 = __builtin_bit_cast(unsigned short, (__bf16)q0);
    unsigned int b1 = __builtin_bit_cast(unsigned short, (__bf16)q1);
    unsigned int b2 = __builtin_bit_cast(unsigned short, (__bf16)q2);
    unsigned int b3 = __builtin_bit_cast(unsigned short, (__bf16)q3);
    uint2 p; p.x = b0 | (b1 << 16); p.y = b2 | (b3 << 16);
    *(uint2*)(wq + (size_t)w * 1048576 + pos) = p;
    if (blockIdx.x == 0 && threadIdx.x == 0) wm[w] = ms;   // weight multiplier = clip(mean|W|,EPS)
}

// ---------------- per-token int8 absmax act quant (stores integer values as bf16) ----------------
__global__ __launch_bounds__(256) void k_actq(const float* __restrict__ in, __bf16* __restrict__ outq,
                                              float* __restrict__ rs) {
    int t = blockIdx.x, tid = threadIdx.x;
    const float* row = in + (size_t)t * 1024;
    f32x4 v = *(const f32x4*)(row + tid * 4);
    float am = fmaxf(fmaxf(fabsf(v.x), fabsf(v.y)), fmaxf(fabsf(v.z), fabsf(v.w)));
#pragma unroll
    for (int off = 1; off < 64; off <<= 1) am = fmaxf(am, __shfl_xor(am, off));
    __shared__ float red[4];
    if ((tid & 63) == 0) red[tid >> 6] = am;
    __syncthreads();
    am = fmaxf(fmaxf(red[0], red[1]), fmaxf(red[2], red[3]));
    am = fmaxf(am, EPSV);                    // clip(absmax, EPS)
    float scale = 127.0f / am;
    float q0 = fminf(fmaxf(rintf(v.x * scale), -128.f), 127.f);
    float q1 = fminf(fmaxf(rintf(v.y * scale), -128.f), 127.f);
    float q2 = fminf(fmaxf(rintf(v.z * scale), -128.f), 127.f);
    float q3 = fminf(fmaxf(rintf(v.w * scale), -128.f), 127.f);
    unsigned int b0 = __builtin_bit_cast(unsigned short, (__bf16)q0);
    unsigned int b1 = __builtin_bit_cast(unsigned short, (__bf16)q1);
    unsigned int b2 = __builtin_bit_cast(unsigned short, (__bf16)q2);
    unsigned int b3 = __builtin_bit_cast(unsigned short, (__bf16)q3);
    uint2 p; p.x = b0 | (b1 << 16); p.y = b2 | (b3 << 16);
    *(uint2*)(outq + (size_t)t * 1024 + tid * 4) = p;
    if (tid == 0) rs[t] = am / 127.0f;       // 1/scale
}

// ---------------- GEMM: out[m][n] = sum_k X[m][k] * W[n][k], scaled by rs[m]*wm ----------------
// MODE 0: z=0/1 -> bf16 (b,h,s,hd) q/k; z=2 -> swapped operands, writes V^T (bh,hd,s) directly
// MODE 1: write fp32 into d_out (T x 1024)
template <int MODE>
__global__ __launch_bounds__(256) void k_gemm(const __bf16* __restrict__ X, const __bf16* __restrict__ Wb,
                                              const float* __restrict__ rs, const float* __restrict__ wm,
                                              __bf16* __restrict__ o0, __bf16* __restrict__ o1,
                                              __bf16* __restrict__ o2, float* __restrict__ outf) {
    __shared__ __attribute__((aligned(16))) __bf16 As[128 * 32];
    __shared__ __attribute__((aligned(16))) __bf16 Bs[128 * 32];
    int tid = threadIdx.x;
    int wave = tid >> 6, lane = tid & 63, g = lane >> 4, l = lane & 15;
    int m0 = blockIdx.x * 128, n0 = blockIdx.y * 128;
    int z = blockIdx.z;
    const __bf16* W = Wb + (size_t)z * 1048576;
    float wmv = wm[z];
    f32x4 acc[4][4] = {};
    int srow0 = wave * 16 + (lane >> 2);
    int scol = (lane & 3) * 8;
    const __bf16* Ag = X + (size_t)(m0 + srow0) * 1024 + scol;
    const __bf16* Bg = W + (size_t)(n0 + srow0) * 1024 + scol;
    __bf16* ldsA = As + wave * 512;
    __bf16* ldsB = Bs + wave * 512;
    int wrow = (wave >> 1) * 64, wcol = (wave & 1) * 64;
    bool vswap = (MODE == 0) && (z == 2);
    for (int k0 = 0; k0 < 1024; k0 += 32) {
        __syncthreads();
        gload16(Ag + k0,             ldsA);
        gload16(Ag + 64 * 1024 + k0, ldsA + 2048);
        gload16(Bg + k0,             ldsB);
        gload16(Bg + 64 * 1024 + k0, ldsB + 2048);
        __syncthreads();
        bf16x8 af[4], bfr[4];
#pragma unroll
        for (int i = 0; i < 4; i++) af[i]  = *(const bf16x8*)&As[(wrow + i * 16 + l) * 32 + 8 * g];
#pragma unroll
        for (int i = 0; i < 4; i++) bfr[i] = *(const bf16x8*)&Bs[(wcol + i * 16 + l) * 32 + 8 * g];
        if (vswap) {
#pragma unroll
            for (int mi = 0; mi < 4; mi++)
#pragma unroll
                for (int ni = 0; ni < 4; ni++)
                    acc[mi][ni] = mfma16(bfr[ni], af[mi], acc[mi][ni]);
        } else {
#pragma unroll
            for (int mi = 0; mi < 4; mi++)
#pragma unroll
                for (int ni = 0; ni < 4; ni++)
                    acc[mi][ni] = mfma16(af[mi], bfr[ni], acc[mi][ni]);
        }
    }
    if (vswap) {
#pragma unroll
        for (int mi = 0; mi < 4; mi++) {
            int m = m0 + wrow + mi * 16 + l;
            float rsm = rs[m] * wmv;
            int b = m >> 11, s2 = m & 2047;
#pragma unroll
            for (int ni = 0; ni < 4; ni++) {
                int nb = n0 + wcol + ni * 16 + 4 * g;
#pragma unroll
                for (int r = 0; r < 4; r++) {
                    int n = nb + r;
                    int h = n >> 6, hd = n & 63;
                    o2[((size_t)(b * 16 + h) * 64 + hd) * 2048 + s2] = (__bf16)(acc[mi][ni][r] * rsm);
                }
            }
        }
        return;
    }
#pragma unroll
    for (int mi = 0; mi < 4; mi++) {
        int mbase = m0 + wrow + mi * 16 + 4 * g;
        f32x4 rv = {rs[mbase], rs[mbase + 1], rs[mbase + 2], rs[mbase + 3]};
#pragma unroll
        for (int ni = 0; ni < 4; ni++) {
            int n = n0 + wcol + ni * 16 + l;
#pragma unroll
            for (int r = 0; r < 4; r++) {
                float v = acc[mi][ni][r] * (rv[r] * wmv);
                if constexpr (MODE == 0) {
                    int m = mbase + r;
                    int b = m >> 11, s2 = m & 2047;
                    int h = n >> 6, hd = n & 63;
                    __bf16* dst = (z == 0) ? o0 : o1;
                    dst[(((size_t)(b * 16 + h)) * 2048 + s2) * 64 + hd] = (__bf16)v;
                } else {
                    outf[(size_t)(mbase + r) * 1024 + n] = v;
                }
            }
        }
    }
}

// ---------------- causal flash attention: 8 waves/block, 128-row Q slab, double-buffered LDS K/V^T ----------------
// q/k [bh][s][hd] bf16, vt [bh][hd][s] bf16 -> attn (B,S,D) fp32.
// K/V tiles staged via global_load_lds (16B) with both-sides XOR swizzle; 1 barrier/tile.
__global__ __launch_bounds__(512) void k_attn(const __bf16* __restrict__ qg, const __bf16* __restrict__ kb,
                                              const __bf16* __restrict__ vt, float* __restrict__ attn) {
    __shared__ __attribute__((aligned(16))) __bf16 Ks[2][4096];   // [key 64][d 64] swizzled
    __shared__ __attribute__((aligned(16))) __bf16 Vs[2][4096];   // [hd 64][key 64] swizzled
    __shared__ __attribute__((aligned(16))) __bf16 Ps[8][1024];   // per-wave 16x64 P, swizzled
    int tid = threadIdx.x, w = tid >> 6, lane = tid & 63, g = lane >> 4, l = lane & 15;
    int bh = blockIdx.y, bq = bh >> 4, h = bh & 15;
    int q0 = blockIdx.x * 128;
    size_t bhq = (size_t)bh * 2048 * 64;
    int qlo = q0 + w * 16, qmax = qlo + 15;
    int qrow = qlo + l;
    bf16x8 aq0 = *(const bf16x8*)(qg + bhq + (size_t)qrow * 64 + 8 * g);
    bf16x8 aq1 = *(const bf16x8*)(qg + bhq + (size_t)qrow * 64 + 32 + 8 * g);
    f32x4 o[4] = {};
    float mreg[4], lsum[4];
#pragma unroll
    for (int r = 0; r < 4; r++) { mreg[r] = -INFINITY; lsum[r] = 0.f; }
    char* Pw = (char*)&Ps[w][0];
    int psw = (l & 7) << 4;
    // staging: wave w stages rows 8w..8w+7 of each 64x(64x2B) tile.
    // LDS dest is linear (base + lane*16); global source column pre-swizzled so that
    // read-side "byte ^ ((row&7)<<4)" finds the right data (rule 21 both-sides).
    int sRow = w * 8 + (lane >> 3);                       // tile row this lane feeds
    int sCol = ((lane & 7) ^ (lane >> 3)) << 3;           // bf16 elements (16B units ^ row&7)
    const __bf16* Kg = kb + bhq + (size_t)sRow * 64 + sCol;
    const __bf16* Vg = vt + bhq + (size_t)sRow * 2048 + sCol;
    int nt = 2 * (blockIdx.x + 1);
    // prologue: stage tile 0 into buf 0
    gload16(Kg, &Ks[0][w * 512]);
    gload16(Vg, &Vs[0][w * 512]);
    __syncthreads();
    for (int ti = 0; ti < nt; ti++) {
        int t0 = ti * 64;
        int tn = ti + 1;
        if (tn < nt) {   // issue next-tile stage; lands during compute (vmcnt drained at barrier)
            gload16(Kg + (size_t)tn * 4096, &Ks[tn & 1][w * 512]);
            gload16(Vg + tn * 64,           &Vs[tn & 1][w * 512]);
        }
        if (t0 <= qmax) {
            const char* Kb = (const char*)&Ks[ti & 1][0];
            const char* Vb = (const char*)&Vs[ti & 1][0];
            // S = Q.K^T / 8
            f32x4 sv[4];
            __builtin_amdgcn_s_setprio(1);
#pragma unroll
            for (int nb = 0; nb < 4; nb++) {
                int kr = nb * 16 + l;
                const char* kbase = Kb + kr * 128;
                int sz = (kr & 7) << 4;
                bf16x8 bk0 = *(const bf16x8*)(kbase + ((16 * g) ^ sz));
                bf16x8 bk1 = *(const bf16x8*)(kbase + ((64 + 16 * g) ^ sz));
                f32x4 a = {};
                a = mfma16(aq0, bk0, a);
                a = mfma16(aq1, bk1, a);
                sv[nb] = a * 0.125f;
            }
            __builtin_amdgcn_s_setprio(0);
            if (t0 + 63 > qlo) {   // diagonal tile: causal mask
#pragma unroll
                for (int nb = 0; nb < 4; nb++)
#pragma unroll
                    for (int r = 0; r < 4; r++) {
                        int key = t0 + nb * 16 + l;
                        int q = qlo + 4 * g + r;
                        if (key > q) sv[nb][r] = -INFINITY;
                    }
            }
            // online softmax (rows on (g, reg); 16 lanes hold keys)
            float corr[4];
#pragma unroll
            for (int r = 0; r < 4; r++) {
                float v = fmaxf(fmaxf(sv[0][r], sv[1][r]), fmaxf(sv[2][r], sv[3][r]));
                v = fmaxf(v, __shfl_xor(v, 1));
                v = fmaxf(v, __shfl_xor(v, 2));
                v = fmaxf(v, __shfl_xor(v, 4));
                v = fmaxf(v, __shfl_xor(v, 8));
                float mnew = fmaxf(mreg[r], v);
                corr[r] = __expf(mreg[r] - mnew);
                mreg[r] = mnew;
            }
            float ps[4] = {0.f, 0.f, 0.f, 0.f};
#pragma unroll
            for (int nb = 0; nb < 4; nb++)
#pragma unroll
                for (int r = 0; r < 4; r++) {
                    float pe = __expf(sv[nb][r] - mreg[r]);
                    sv[nb][r] = pe;
                    ps[r] += pe;
                }
#pragma unroll
            for (int r = 0; r < 4; r++) {
                float sm = ps[r];
                sm += __shfl_xor(sm, 1);
                sm += __shfl_xor(sm, 2);
                sm += __shfl_xor(sm, 4);
                sm += __shfl_xor(sm, 8);
                lsum[r] = lsum[r] * corr[r] + sm;
#pragma unroll
                for (int hb = 0; hb < 4; hb++) o[hb][r] = o[hb][r] * corr[r];
            }
            // P -> per-wave LDS (bf16), re-read as A fragments (wave-synchronous)
#pragma unroll
            for (int nb = 0; nb < 4; nb++)
#pragma unroll
                for (int r = 0; r < 4; r++) {
                    int prow = 4 * g + r;
                    *(__bf16*)(Pw + prow * 128 + ((nb * 32 + 2 * l) ^ ((prow & 7) << 4))) = (__bf16)sv[nb][r];
                }
            bf16x8 pa0 = *(const bf16x8*)(Pw + l * 128 + ((16 * g) ^ psw));
            bf16x8 pa1 = *(const bf16x8*)(Pw + l * 128 + ((64 + 16 * g) ^ psw));
            __builtin_amdgcn_s_setprio(1);
#pragma unroll
            for (int hb = 0; hb < 4; hb++) {
                int vr = hb * 16 + l;
                const char* vbase = Vb + vr * 128;
                int sz = (vr & 7) << 4;
                bf16x8 v0 = *(const bf16x8*)(vbase + ((16 * g) ^ sz));
                bf16x8 v1 = *(const bf16x8*)(vbase + ((64 + 16 * g) ^ sz));
                o[hb] = mfma16(pa0, v0, o[hb]);
                o[hb] = mfma16(pa1, v1, o[hb]);
            }
            __builtin_amdgcn_s_setprio(0);
        }
        __syncthreads();
    }
    // epilogue: write (B,S,D) fp32
#pragma unroll
    for (int r = 0; r < 4; r++) {
        float inv = 1.0f / lsum[r];
        int q = qlo + 4 * g + r;
        float* dst = attn + ((size_t)(bq * 2048 + q)) * 1024 + h * 64 + l;
#pragma unroll
        for (int hb = 0; hb < 4; hb++) dst[hb * 16] = o[hb][r] * inv;
    }
}

extern "C" void kernel_launch(void* const* d_in, const int* in_sizes, int n_in,
                              void* d_out, int out_size, void* d_ws, size_t ws_size,
                              hipStream_t stream) {
    const float* x  = (const float*)d_in[0];
    // d_in[1] = mask: guaranteed causal tril, hardcoded in k_attn
    const float* Wq = (const float*)d_in[2];
    const float* Wk = (const float*)d_in[3];
    const float* Wv = (const float*)d_in[4];
    const float* Wo = (const float*)d_in[5];
    float* out = (float*)d_out;
    char* ws = (char*)d_ws;

    double* wsumd = (double*)(ws + 0);                       // 32 B
    float*  wmv   = (float*)(ws + 256);                      // 16 B
    __bf16* wqall = (__bf16*)(ws + 512);                     // 8 MB (4 x 1M bf16)
    __bf16* xq    = (__bf16*)(ws + 512 + 8388608);           // 8 MB
    float*  rsx   = (float*)(ws + 512 + 16777216);           // 16 KB
    float*  rso   = (float*)(ws + 512 + 16777216 + 16384);   // 16 KB
    char*   big   = ws + 512 + 16777216 + 32768;
    __bf16* qbuf  = (__bf16*)(big);                          // 8 MB
    __bf16* kbuf  = (__bf16*)(big + 8388608);                // 8 MB
    __bf16* oq    = (__bf16*)(big + 16777216);               // 8 MB
    __bf16* vtb   = (__bf16*)(big + 25165824);               // 8 MB (V^T, written by k_gemm z=2)
    float*  attn  = (float*)(big + 33554432);                // 16 MB

    hipMemsetAsync(ws, 0, 512, stream);
    k_wsum<<<dim3(256), 256, 0, stream>>>(Wq, Wk, Wv, Wo, wsumd);
    k_wquant<<<dim3(1024, 4), 256, 0, stream>>>(Wq, Wk, Wv, Wo, wsumd, wqall, wmv);
    k_actq<<<dim3(4096), 256, 0, stream>>>(x, xq, rsx);
    k_gemm<0><<<dim3(32, 8, 3), 256, 0, stream>>>(xq, wqall, rsx, wmv, qbuf, kbuf, vtb, nullptr);
    k_attn<<<dim3(16, 32), 512, 0, stream>>>(qbuf, kbuf, vtb, attn);
    k_actq<<<dim3(4096), 256, 0, stream>>>(attn, oq, rso);
    k_gemm<1><<<dim3(32, 8, 1), 256, 0, stream>>>(oq, wqall + 3 * 1048576, rso, wmv + 3,
                                                  nullptr, nullptr, nullptr, out);
}

// Round 5
// 254.055 us; speedup vs baseline: 1.3123x; 1.1040x over previous
//
#include <hip/hip_runtime.h>
#include <hip/hip_bf16.h>
#include <math.h>

// BitLinearAttention on gfx950.
// B=2, S=2048, D=1024, H=16, Hd=64, T=B*S=4096. All GEMMs done as exact-integer
// bf16 MFMA (qint in [-128,127], ternary weights), scales applied in epilogue.

typedef float  f32x4  __attribute__((ext_vector_type(4)));
typedef __bf16 bf16x8 __attribute__((ext_vector_type(8)));
typedef __bf16 bf16x4 __attribute__((ext_vector_type(4)));
typedef unsigned int u32x4 __attribute__((ext_vector_type(4)));

#define EPSV 1e-5f

__device__ __forceinline__ f32x4 mfma16(bf16x8 a, bf16x8 b, f32x4 c) {
    return __builtin_amdgcn_mfma_f32_16x16x32_bf16(a, b, c, 0, 0, 0);
}

__device__ __forceinline__ void gload16(const void* g, void* lds) {
    __builtin_amdgcn_global_load_lds((const __attribute__((address_space(1))) unsigned int*)g,
                                     (__attribute__((address_space(3))) unsigned int*)lds, 16, 0, 0);
}

// ---------------- weight |.| sum (fp64 accumulate) ----------------
__global__ __launch_bounds__(256) void k_wsum(const float* __restrict__ w0, const float* __restrict__ w1,
                                              const float* __restrict__ w2, const float* __restrict__ w3,
                                              double* __restrict__ wsum) {
    int w = blockIdx.x >> 6, chunk = blockIdx.x & 63, tid = threadIdx.x;
    const float* W = (w == 0) ? w0 : (w == 1) ? w1 : (w == 2) ? w2 : w3;
    const float* base = W + (size_t)chunk * 16384;
    float s = 0.f;
#pragma unroll
    for (int i = 0; i < 16; i++) {
        f32x4 v = *(const f32x4*)(base + i * 1024 + tid * 4);
        s += fabsf(v.x) + fabsf(v.y) + fabsf(v.z) + fabsf(v.w);
    }
#pragma unroll
    for (int off = 1; off < 64; off <<= 1) s += __shfl_xor(s, off);
    __shared__ float red[4];
    if ((tid & 63) == 0) red[tid >> 6] = s;
    __syncthreads();
    if (tid == 0) {
        double t = (double)red[0] + (double)red[1] + (double)red[2] + (double)red[3];
        atomicAdd(&wsum[w], t);
    }
}

// ---------------- ternary weight quantization ----------------
__global__ __launch_bounds__(256) void k_wquant(const float* __restrict__ w0, const float* __restrict__ w1,
                                                const float* __restrict__ w2, const float* __restrict__ w3,
                                                const double* __restrict__ wsum,
                                                __bf16* __restrict__ wq, float* __restrict__ wm) {
    int w = blockIdx.y;
    const float* W = (w == 0) ? w0 : (w == 1) ? w1 : (w == 2) ? w2 : w3;
    float mean = (float)(wsum[w] * (1.0 / 1048576.0));
    float ms = fmaxf(mean, EPSV);           // clip(mean, EPS)
    float scale = 1.0f / ms;
    int pos = blockIdx.x * 1024 + threadIdx.x * 4;
    f32x4 v = *(const f32x4*)(W + pos);
    float q0 = fminf(fmaxf(rintf(v.x * scale), -1.f), 1.f);
    float q1 = fminf(fmaxf(rintf(v.y * scale), -1.f), 1.f);
    float q2 = fminf(fmaxf(rintf(v.z * scale), -1.f), 1.f);
    float q3 = fminf(fmaxf(rintf(v.w * scale), -1.f), 1.f);
    unsigned int b0 = __builtin_bit_cast(unsigned short, (__bf16)q0);
    unsigned int b1 = __builtin_bit_cast(unsigned short, (__bf16)q1);
    unsigned int b2 = __builtin_bit_cast(unsigned short, (__bf16)q2);
    unsigned int b3 = __builtin_bit_cast(unsigned short, (__bf16)q3);
    uint2 p; p.x = b0 | (b1 << 16); p.y = b2 | (b3 << 16);
    *(uint2*)(wq + (size_t)w * 1048576 + pos) = p;
    if (blockIdx.x == 0 && threadIdx.x == 0) wm[w] = ms;   // weight multiplier = clip(mean|W|,EPS)
}

// ---------------- per-token int8 absmax act quant (stores integer values as bf16) ----------------
__global__ __launch_bounds__(256) void k_actq(const float* __restrict__ in, __bf16* __restrict__ outq,
                                              float* __restrict__ rs) {
    int t = blockIdx.x, tid = threadIdx.x;
    const float* row = in + (size_t)t * 1024;
    f32x4 v = *(const f32x4*)(row + tid * 4);
    float am = fmaxf(fmaxf(fabsf(v.x), fabsf(v.y)), fmaxf(fabsf(v.z), fabsf(v.w)));
#pragma unroll
    for (int off = 1; off < 64; off <<= 1) am = fmaxf(am, __shfl_xor(am, off));
    __shared__ float red[4];
    if ((tid & 63) == 0) red[tid >> 6] = am;
    __syncthreads();
    am = fmaxf(fmaxf(red[0], red[1]), fmaxf(red[2], red[3]));
    am = fmaxf(am, EPSV);                    // clip(absmax, EPS)
    float scale = 127.0f / am;
    float q0 = fminf(fmaxf(rintf(v.x * scale), -128.f), 127.f);
    float q1 = fminf(fmaxf(rintf(v.y * scale), -128.f), 127.f);
    float q2 = fminf(fmaxf(rintf(v.z * scale), -128.f), 127.f);
    float q3 = fminf(fmaxf(rintf(v.w * scale), -128.f), 127.f);
    unsigned int b0 = __builtin_bit_cast(unsigned short, (__bf16)q0);
    unsigned int b1 = __builtin_bit_cast(unsigned short, (__bf16)q1);
    unsigned int b2 = __builtin_bit_cast(unsigned short, (__bf16)q2);
    unsigned int b3 = __builtin_bit_cast(unsigned short, (__bf16)q3);
    uint2 p; p.x = b0 | (b1 << 16); p.y = b2 | (b3 << 16);
    *(uint2*)(outq + (size_t)t * 1024 + tid * 4) = p;
    if (tid == 0) rs[t] = am / 127.0f;       // 1/scale
}

// ---------------- GEMM: out[m][n] = sum_k X[m][k] * W[n][k], scaled by rs[m]*wm ----------------
// MODE 0: z=0/1 -> bf16 (b,h,s,hd) q/k; z=2 -> swapped operands, writes V^T (bh,hd,s) directly
// MODE 1: write fp32 into d_out (T x 1024)
template <int MODE>
__global__ __launch_bounds__(256) void k_gemm(const __bf16* __restrict__ X, const __bf16* __restrict__ Wb,
                                              const float* __restrict__ rs, const float* __restrict__ wm,
                                              __bf16* __restrict__ o0, __bf16* __restrict__ o1,
                                              __bf16* __restrict__ o2, float* __restrict__ outf) {
    __shared__ __attribute__((aligned(16))) __bf16 As[128 * 32];
    __shared__ __attribute__((aligned(16))) __bf16 Bs[128 * 32];
    int tid = threadIdx.x;
    int wave = tid >> 6, lane = tid & 63, g = lane >> 4, l = lane & 15;
    int m0 = blockIdx.x * 128, n0 = blockIdx.y * 128;
    int z = blockIdx.z;
    const __bf16* W = Wb + (size_t)z * 1048576;
    float wmv = wm[z];
    f32x4 acc[4][4] = {};
    int srow0 = wave * 16 + (lane >> 2);
    int scol = (lane & 3) * 8;
    const __bf16* Ag = X + (size_t)(m0 + srow0) * 1024 + scol;
    const __bf16* Bg = W + (size_t)(n0 + srow0) * 1024 + scol;
    __bf16* ldsA = As + wave * 512;
    __bf16* ldsB = Bs + wave * 512;
    int wrow = (wave >> 1) * 64, wcol = (wave & 1) * 64;
    bool vswap = (MODE == 0) && (z == 2);
    for (int k0 = 0; k0 < 1024; k0 += 32) {
        __syncthreads();
        gload16(Ag + k0,             ldsA);
        gload16(Ag + 64 * 1024 + k0, ldsA + 2048);
        gload16(Bg + k0,             ldsB);
        gload16(Bg + 64 * 1024 + k0, ldsB + 2048);
        __syncthreads();
        bf16x8 af[4], bfr[4];
#pragma unroll
        for (int i = 0; i < 4; i++) af[i]  = *(const bf16x8*)&As[(wrow + i * 16 + l) * 32 + 8 * g];
#pragma unroll
        for (int i = 0; i < 4; i++) bfr[i] = *(const bf16x8*)&Bs[(wcol + i * 16 + l) * 32 + 8 * g];
        if (vswap) {
#pragma unroll
            for (int mi = 0; mi < 4; mi++)
#pragma unroll
                for (int ni = 0; ni < 4; ni++)
                    acc[mi][ni] = mfma16(bfr[ni], af[mi], acc[mi][ni]);
        } else {
#pragma unroll
            for (int mi = 0; mi < 4; mi++)
#pragma unroll
                for (int ni = 0; ni < 4; ni++)
                    acc[mi][ni] = mfma16(af[mi], bfr[ni], acc[mi][ni]);
        }
    }
    if (vswap) {
#pragma unroll
        for (int mi = 0; mi < 4; mi++) {
            int m = m0 + wrow + mi * 16 + l;
            float rsm = rs[m] * wmv;
            int b = m >> 11, s2 = m & 2047;
#pragma unroll
            for (int ni = 0; ni < 4; ni++) {
                int nb = n0 + wcol + ni * 16 + 4 * g;
#pragma unroll
                for (int r = 0; r < 4; r++) {
                    int n = nb + r;
                    int h = n >> 6, hd = n & 63;
                    o2[((size_t)(b * 16 + h) * 64 + hd) * 2048 + s2] = (__bf16)(acc[mi][ni][r] * rsm);
                }
            }
        }
        return;
    }
#pragma unroll
    for (int mi = 0; mi < 4; mi++) {
        int mbase = m0 + wrow + mi * 16 + 4 * g;
        f32x4 rv = {rs[mbase], rs[mbase + 1], rs[mbase + 2], rs[mbase + 3]};
#pragma unroll
        for (int ni = 0; ni < 4; ni++) {
            int n = n0 + wcol + ni * 16 + l;
#pragma unroll
            for (int r = 0; r < 4; r++) {
                float v = acc[mi][ni][r] * (rv[r] * wmv);
                if constexpr (MODE == 0) {
                    int m = mbase + r;
                    int b = m >> 11, s2 = m & 2047;
                    int h = n >> 6, hd = n & 63;
                    __bf16* dst = (z == 0) ? o0 : o1;
                    dst[(((size_t)(b * 16 + h)) * 2048 + s2) * 64 + hd] = (__bf16)v;
                } else {
                    outf[(size_t)(mbase + r) * 1024 + n] = v;
                }
            }
        }
    }
}

// ---------------- causal flash attention v3: swapped-operand QK^T / PV, lane-local softmax ----------------
// q/k [bh][s][hd] bf16, vt [bh][hd][s] bf16 -> attn (B,S,D) fp32.
// 8 waves/block, 128-row Q slab, triple-buffered LDS K/V^T staged via global_load_lds
// (both-sides XOR swizzle), counted vmcnt pipeline (2 tiles in flight), P stays in registers.
__global__ __launch_bounds__(512) void k_attn(const __bf16* __restrict__ qg, const __bf16* __restrict__ kb,
                                              const __bf16* __restrict__ vt, float* __restrict__ attn) {
    __shared__ __attribute__((aligned(16))) __bf16 Ks[3][4096];   // [key 64][d 64], 16B-chunk swizzled
    __shared__ __attribute__((aligned(16))) __bf16 Vs[3][4096];   // [hd 64][key 64], 16B-chunk swizzled
    int tid = threadIdx.x, w = tid >> 6, lane = tid & 63, g = lane >> 4, l = lane & 15;
    int bh = blockIdx.y, bq = bh >> 4, h = bh & 15;
    int q0 = blockIdx.x * 128;
    size_t bhq = (size_t)bh * 2048 * 64;
    int qlo = q0 + w * 16, qmax = qlo + 15;
    int qrow = qlo + l;
    // Q fragments (B-operand: row = qrow(lane&15), k = 8g+j)
    bf16x8 aq0 = *(const bf16x8*)(qg + bhq + (size_t)qrow * 64 + 8 * g);
    bf16x8 aq1 = *(const bf16x8*)(qg + bhq + (size_t)qrow * 64 + 32 + 8 * g);
    asm volatile("" : "+v"(aq0), "+v"(aq1));   // pin Q in regs; places the vmcnt wait here
    f32x4 o[4] = {};
    float mreg = -INFINITY, lsum = 0.f;
    // staging: wave w stages rows 8w..8w+7; linear LDS dest, inverse-swizzled global source
    int sRow = w * 8 + (lane >> 3);
    int sCol = ((lane & 7) ^ (lane >> 3)) << 3;
    const __bf16* Kg = kb + bhq + (size_t)sRow * 64 + sCol;
    const __bf16* Vg = vt + bhq + (size_t)sRow * 2048 + sCol;
    int nt = 2 * (blockIdx.x + 1);
    // prologue: stage tiles 0,1
    gload16(Kg,        &Ks[0][w * 512]);
    gload16(Vg,        &Vs[0][w * 512]);
    gload16(Kg + 4096, &Ks[1][w * 512]);
    gload16(Vg + 64,   &Vs[1][w * 512]);
    int cur = 0;
    int swk = (l & 7) << 4;   // K-frag read swizzle (row kr: kr&7 == l&7)
    for (int t = 0; t < nt; ++t) {
        if (t < nt - 1) { asm volatile("s_waitcnt vmcnt(2)"); }
        else            { asm volatile("s_waitcnt vmcnt(0)"); }
        __builtin_amdgcn_s_barrier();
        __builtin_amdgcn_sched_barrier(0);
        int tn = t + 2;
        if (tn < nt) {
            int nbuf = cur + 2; if (nbuf >= 3) nbuf -= 3;
            gload16(Kg + (size_t)tn * 4096, &Ks[nbuf][w * 512]);
            gload16(Vg + tn * 64,           &Vs[nbuf][w * 512]);
        }
        int t0 = t * 64;
        if (t0 <= qmax) {
            const char* Kb = (const char*)&Ks[cur][0];
            const char* Vb = (const char*)&Vs[cur][0];
            // S^T = K.Q^T / 8: sv[nb] row=key(16nb+4g+r), col=qrow(l)
            f32x4 sv[4];
            __builtin_amdgcn_s_setprio(1);
#pragma unroll
            for (int nb = 0; nb < 4; nb++) {
                const char* kbase = Kb + (nb * 16 + l) * 128;
                bf16x8 bk0 = *(const bf16x8*)(kbase + ((16 * g) ^ swk));
                bf16x8 bk1 = *(const bf16x8*)(kbase + ((64 + 16 * g) ^ swk));
                f32x4 a = {};
                a = mfma16(bk0, aq0, a);   // swapped: A=K rows, B=Q rows
                a = mfma16(bk1, aq1, a);
                sv[nb] = a * 0.125f;
            }
            __builtin_amdgcn_s_setprio(0);
            if (t0 + 63 > qlo) {   // diagonal tile: causal mask (key > qrow)
#pragma unroll
                for (int nb = 0; nb < 4; nb++)
#pragma unroll
                    for (int r = 0; r < 4; r++) {
                        int key = t0 + nb * 16 + 4 * g + r;
                        if (key > qrow) sv[nb][r] = -INFINITY;
                    }
            }
            // lane-local row max over 16 held keys, then reduce over g (2 shuffles)
            float pm0 = fmaxf(fmaxf(sv[0][0], sv[0][1]), fmaxf(sv[0][2], sv[0][3]));
            float pm1 = fmaxf(fmaxf(sv[1][0], sv[1][1]), fmaxf(sv[1][2], sv[1][3]));
            float pm2 = fmaxf(fmaxf(sv[2][0], sv[2][1]), fmaxf(sv[2][2], sv[2][3]));
            float pm3 = fmaxf(fmaxf(sv[3][0], sv[3][1]), fmaxf(sv[3][2], sv[3][3]));
            float pm = fmaxf(fmaxf(pm0, pm1), fmaxf(pm2, pm3));
            pm = fmaxf(pm, __shfl_xor(pm, 16));
            pm = fmaxf(pm, __shfl_xor(pm, 32));
            float mnew = fmaxf(mreg, pm);
            float corr = __expf(mreg - mnew);
            mreg = mnew;
            // P = exp(S - m), row sum
            float psum = 0.f;
#pragma unroll
            for (int nb = 0; nb < 4; nb++)
#pragma unroll
                for (int r = 0; r < 4; r++) {
                    float pe = __expf(sv[nb][r] - mnew);
                    sv[nb][r] = pe;
                    psum += pe;
                }
            psum += __shfl_xor(psum, 16);
            psum += __shfl_xor(psum, 32);
            lsum = lsum * corr + psum;
#pragma unroll
            for (int hb = 0; hb < 4; hb++) o[hb] *= corr;
            // pack P into B-frags: slot (g,j) <-> key 32m + 16(j>>2) + 4g + (j&3)  (bijection)
            bf16x8 pf0, pf1;
#pragma unroll
            for (int j = 0; j < 8; j++) {
                pf0[j] = (__bf16)sv[j >> 2][j & 3];
                pf1[j] = (__bf16)sv[2 + (j >> 2)][j & 3];
            }
            // PV swapped: o[hb] row=hd(16hb+4g+r), col=qrow(l); V read in matching slot order
            __builtin_amdgcn_s_setprio(1);
#pragma unroll
            for (int hb = 0; hb < 4; hb++) {
                int vrow = hb * 16 + l;
                const char* vb = Vb + vrow * 128;
                int rsw = vrow & 7;          // == l&7
                int ib = 8 * (g & 1);
                int gh = g >> 1;
                bf16x4 v00 = *(const bf16x4*)(vb + 16 * ((gh + 0) ^ rsw) + ib);
                bf16x4 v01 = *(const bf16x4*)(vb + 16 * ((gh + 2) ^ rsw) + ib);
                bf16x8 vf0 = __builtin_shufflevector(v00, v01, 0, 1, 2, 3, 4, 5, 6, 7);
                o[hb] = mfma16(vf0, pf0, o[hb]);
                bf16x4 v10 = *(const bf16x4*)(vb + 16 * ((gh + 4) ^ rsw) + ib);
                bf16x4 v11 = *(const bf16x4*)(vb + 16 * ((gh + 6) ^ rsw) + ib);
                bf16x8 vf1 = __builtin_shufflevector(v10, v11, 0, 1, 2, 3, 4, 5, 6, 7);
                o[hb] = mfma16(vf1, pf1, o[hb]);
            }
            __builtin_amdgcn_s_setprio(0);
        }
        cur = (cur + 1 == 3) ? 0 : cur + 1;
    }
    // epilogue: lane (l,g) holds q = qlo+l, hd = 16hb+4g+r -> f32x4 stores
    float inv = 1.0f / lsum;
    float* dst = attn + ((size_t)(bq * 2048 + qlo + l)) * 1024 + h * 64 + 4 * g;
#pragma unroll
    for (int hb = 0; hb < 4; hb++) {
        f32x4 vsto = o[hb] * inv;
        *(f32x4*)(dst + 16 * hb) = vsto;
    }
}

extern "C" void kernel_launch(void* const* d_in, const int* in_sizes, int n_in,
                              void* d_out, int out_size, void* d_ws, size_t ws_size,
                              hipStream_t stream) {
    const float* x  = (const float*)d_in[0];
    // d_in[1] = mask: guaranteed causal tril, hardcoded in k_attn
    const float* Wq = (const float*)d_in[2];
    const float* Wk = (const float*)d_in[3];
    const float* Wv = (const float*)d_in[4];
    const float* Wo = (const float*)d_in[5];
    float* out = (float*)d_out;
    char* ws = (char*)d_ws;

    double* wsumd = (double*)(ws + 0);                       // 32 B
    float*  wmv   = (float*)(ws + 256);                      // 16 B
    __bf16* wqall = (__bf16*)(ws + 512);                     // 8 MB (4 x 1M bf16)
    __bf16* xq    = (__bf16*)(ws + 512 + 8388608);           // 8 MB
    float*  rsx   = (float*)(ws + 512 + 16777216);           // 16 KB
    float*  rso   = (float*)(ws + 512 + 16777216 + 16384);   // 16 KB
    char*   big   = ws + 512 + 16777216 + 32768;
    __bf16* qbuf  = (__bf16*)(big);                          // 8 MB
    __bf16* kbuf  = (__bf16*)(big + 8388608);                // 8 MB
    __bf16* oq    = (__bf16*)(big + 16777216);               // 8 MB
    __bf16* vtb   = (__bf16*)(big + 25165824);               // 8 MB (V^T, written by k_gemm z=2)
    float*  attn  = (float*)(big + 33554432);                // 16 MB

    hipMemsetAsync(ws, 0, 512, stream);
    k_wsum<<<dim3(256), 256, 0, stream>>>(Wq, Wk, Wv, Wo, wsumd);
    k_wquant<<<dim3(1024, 4), 256, 0, stream>>>(Wq, Wk, Wv, Wo, wsumd, wqall, wmv);
    k_actq<<<dim3(4096), 256, 0, stream>>>(x, xq, rsx);
    k_gemm<0><<<dim3(32, 8, 3), 256, 0, stream>>>(xq, wqall, rsx, wmv, qbuf, kbuf, vtb, nullptr);
    k_attn<<<dim3(16, 32), 512, 0, stream>>>(qbuf, kbuf, vtb, attn);
    k_actq<<<dim3(4096), 256, 0, stream>>>(attn, oq, rso);
    k_gemm<1><<<dim3(32, 8, 1), 256, 0, stream>>>(oq, wqall + 3 * 1048576, rso, wmv + 3,
                                                  nullptr, nullptr, nullptr, out);
}

// Round 6
// 242.870 us; speedup vs baseline: 1.3728x; 1.0461x over previous
//
#include <hip/hip_runtime.h>
#include <hip/hip_bf16.h>
#include <math.h>

// BitLinearAttention on gfx950.
// B=2, S=2048, D=1024, H=16, Hd=64, T=B*S=4096. All GEMMs done as exact-integer
// bf16 MFMA (qint in [-128,127], ternary weights), scales applied in epilogue.

typedef float  f32x4  __attribute__((ext_vector_type(4)));
typedef __bf16 bf16x8 __attribute__((ext_vector_type(8)));
typedef __bf16 bf16x4 __attribute__((ext_vector_type(4)));
typedef unsigned int u32x4 __attribute__((ext_vector_type(4)));

#define EPSV 1e-5f

__device__ __forceinline__ f32x4 mfma16(bf16x8 a, bf16x8 b, f32x4 c) {
    return __builtin_amdgcn_mfma_f32_16x16x32_bf16(a, b, c, 0, 0, 0);
}

__device__ __forceinline__ void gload16(const void* g, void* lds) {
    __builtin_amdgcn_global_load_lds((const __attribute__((address_space(1))) unsigned int*)g,
                                     (__attribute__((address_space(3))) unsigned int*)lds, 16, 0, 0);
}

// ---------------- weight |.| sum (fp64 accumulate) ----------------
__global__ __launch_bounds__(256) void k_wsum(const float* __restrict__ w0, const float* __restrict__ w1,
                                              const float* __restrict__ w2, const float* __restrict__ w3,
                                              double* __restrict__ wsum) {
    int w = blockIdx.x >> 6, chunk = blockIdx.x & 63, tid = threadIdx.x;
    const float* W = (w == 0) ? w0 : (w == 1) ? w1 : (w == 2) ? w2 : w3;
    const float* base = W + (size_t)chunk * 16384;
    float s = 0.f;
#pragma unroll
    for (int i = 0; i < 16; i++) {
        f32x4 v = *(const f32x4*)(base + i * 1024 + tid * 4);
        s += fabsf(v.x) + fabsf(v.y) + fabsf(v.z) + fabsf(v.w);
    }
#pragma unroll
    for (int off = 1; off < 64; off <<= 1) s += __shfl_xor(s, off);
    __shared__ float red[4];
    if ((tid & 63) == 0) red[tid >> 6] = s;
    __syncthreads();
    if (tid == 0) {
        double t = (double)red[0] + (double)red[1] + (double)red[2] + (double)red[3];
        atomicAdd(&wsum[w], t);
    }
}

// ---------------- ternary weight quantization ----------------
__global__ __launch_bounds__(256) void k_wquant(const float* __restrict__ w0, const float* __restrict__ w1,
                                                const float* __restrict__ w2, const float* __restrict__ w3,
                                                const double* __restrict__ wsum,
                                                __bf16* __restrict__ wq, float* __restrict__ wm) {
    int w = blockIdx.y;
    const float* W = (w == 0) ? w0 : (w == 1) ? w1 : (w == 2) ? w2 : w3;
    float mean = (float)(wsum[w] * (1.0 / 1048576.0));
    float ms = fmaxf(mean, EPSV);           // clip(mean, EPS)
    float scale = 1.0f / ms;
    int pos = blockIdx.x * 1024 + threadIdx.x * 4;
    f32x4 v = *(const f32x4*)(W + pos);
    float q0 = fminf(fmaxf(rintf(v.x * scale), -1.f), 1.f);
    float q1 = fminf(fmaxf(rintf(v.y * scale), -1.f), 1.f);
    float q2 = fminf(fmaxf(rintf(v.z * scale), -1.f), 1.f);
    float q3 = fminf(fmaxf(rintf(v.w * scale), -1.f), 1.f);
    unsigned int b0 = __builtin_bit_cast(unsigned short, (__bf16)q0);
    unsigned int b1 = __builtin_bit_cast(unsigned short, (__bf16)q1);
    unsigned int b2 = __builtin_bit_cast(unsigned short, (__bf16)q2);
    unsigned int b3 = __builtin_bit_cast(unsigned short, (__bf16)q3);
    uint2 p; p.x = b0 | (b1 << 16); p.y = b2 | (b3 << 16);
    *(uint2*)(wq + (size_t)w * 1048576 + pos) = p;
    if (blockIdx.x == 0 && threadIdx.x == 0) wm[w] = ms;   // weight multiplier = clip(mean|W|,EPS)
}

// ---------------- per-token int8 absmax act quant (stores integer values as bf16) ----------------
__global__ __launch_bounds__(256) void k_actq(const float* __restrict__ in, __bf16* __restrict__ outq,
                                              float* __restrict__ rs) {
    int t = blockIdx.x, tid = threadIdx.x;
    const float* row = in + (size_t)t * 1024;
    f32x4 v = *(const f32x4*)(row + tid * 4);
    float am = fmaxf(fmaxf(fabsf(v.x), fabsf(v.y)), fmaxf(fabsf(v.z), fabsf(v.w)));
#pragma unroll
    for (int off = 1; off < 64; off <<= 1) am = fmaxf(am, __shfl_xor(am, off));
    __shared__ float red[4];
    if ((tid & 63) == 0) red[tid >> 6] = am;
    __syncthreads();
    am = fmaxf(fmaxf(red[0], red[1]), fmaxf(red[2], red[3]));
    am = fmaxf(am, EPSV);                    // clip(absmax, EPS)
    float scale = 127.0f / am;
    float q0 = fminf(fmaxf(rintf(v.x * scale), -128.f), 127.f);
    float q1 = fminf(fmaxf(rintf(v.y * scale), -128.f), 127.f);
    float q2 = fminf(fmaxf(rintf(v.z * scale), -128.f), 127.f);
    float q3 = fminf(fmaxf(rintf(v.w * scale), -128.f), 127.f);
    unsigned int b0 = __builtin_bit_cast(unsigned short, (__bf16)q0);
    unsigned int b1 = __builtin_bit_cast(unsigned short, (__bf16)q1);
    unsigned int b2 = __builtin_bit_cast(unsigned short, (__bf16)q2);
    unsigned int b3 = __builtin_bit_cast(unsigned short, (__bf16)q3);
    uint2 p; p.x = b0 | (b1 << 16); p.y = b2 | (b3 << 16);
    *(uint2*)(outq + (size_t)t * 1024 + tid * 4) = p;
    if (tid == 0) rs[t] = am / 127.0f;       // 1/scale
}

// ---------------- GEMM: out[m][n] = sum_k X[m][k] * W[n][k], scaled by rs[m]*wm ----------------
// 2-phase double-buffered: STAGE(next) issued before compute(cur); one barrier per K-step.
// MODE 0: z=0/1 -> bf16 (b,h,s,hd) q/k; z=2 -> swapped operands, writes V^T (bh,hd,s) directly
// MODE 1: write fp32 into d_out (T x 1024)
template <int MODE>
__global__ __launch_bounds__(256) void k_gemm(const __bf16* __restrict__ X, const __bf16* __restrict__ Wb,
                                              const float* __restrict__ rs, const float* __restrict__ wm,
                                              __bf16* __restrict__ o0, __bf16* __restrict__ o1,
                                              __bf16* __restrict__ o2, float* __restrict__ outf) {
    __shared__ __attribute__((aligned(16))) __bf16 As[2][4096];
    __shared__ __attribute__((aligned(16))) __bf16 Bs[2][4096];
    int tid = threadIdx.x;
    int wave = tid >> 6, lane = tid & 63, g = lane >> 4, l = lane & 15;
    int m0 = blockIdx.x * 128, n0 = blockIdx.y * 128;
    int z = blockIdx.z;
    const __bf16* W = Wb + (size_t)z * 1048576;
    float wmv = wm[z];
    f32x4 acc[4][4] = {};
    int srow0 = wave * 16 + (lane >> 2);
    int scol = (lane & 3) * 8;
    const __bf16* Ag = X + (size_t)(m0 + srow0) * 1024 + scol;
    const __bf16* Bg = W + (size_t)(n0 + srow0) * 1024 + scol;
    int woff = wave * 512;
    int wrow = (wave >> 1) * 64, wcol = (wave & 1) * 64;
    bool vswap = (MODE == 0) && (z == 2);
    // prologue: stage k0=0 into buf 0
    gload16(Ag,             &As[0][woff]);
    gload16(Ag + 64 * 1024, &As[0][woff + 2048]);
    gload16(Bg,             &Bs[0][woff]);
    gload16(Bg + 64 * 1024, &Bs[0][woff + 2048]);
    __syncthreads();
    for (int k0 = 0; k0 < 1024; k0 += 32) {
        int cur = (k0 >> 5) & 1;
        if (k0 + 32 < 1024) {   // stage next tile into other buffer; lands under compute
            int nxt = cur ^ 1;
            gload16(Ag + k0 + 32,             &As[nxt][woff]);
            gload16(Ag + 64 * 1024 + k0 + 32, &As[nxt][woff + 2048]);
            gload16(Bg + k0 + 32,             &Bs[nxt][woff]);
            gload16(Bg + 64 * 1024 + k0 + 32, &Bs[nxt][woff + 2048]);
        }
        bf16x8 af[4], bfr[4];
#pragma unroll
        for (int i = 0; i < 4; i++) af[i]  = *(const bf16x8*)&As[cur][(wrow + i * 16 + l) * 32 + 8 * g];
#pragma unroll
        for (int i = 0; i < 4; i++) bfr[i] = *(const bf16x8*)&Bs[cur][(wcol + i * 16 + l) * 32 + 8 * g];
        if (vswap) {
#pragma unroll
            for (int mi = 0; mi < 4; mi++)
#pragma unroll
                for (int ni = 0; ni < 4; ni++)
                    acc[mi][ni] = mfma16(bfr[ni], af[mi], acc[mi][ni]);
        } else {
#pragma unroll
            for (int mi = 0; mi < 4; mi++)
#pragma unroll
                for (int ni = 0; ni < 4; ni++)
                    acc[mi][ni] = mfma16(af[mi], bfr[ni], acc[mi][ni]);
        }
        __syncthreads();   // drains vmcnt(0): next buf staged; all waves done reading cur
    }
    if (vswap) {
#pragma unroll
        for (int mi = 0; mi < 4; mi++) {
            int m = m0 + wrow + mi * 16 + l;
            float rsm = rs[m] * wmv;
            int b = m >> 11, s2 = m & 2047;
#pragma unroll
            for (int ni = 0; ni < 4; ni++) {
                int nb = n0 + wcol + ni * 16 + 4 * g;
#pragma unroll
                for (int r = 0; r < 4; r++) {
                    int n = nb + r;
                    int h = n >> 6, hd = n & 63;
                    o2[((size_t)(b * 16 + h) * 64 + hd) * 2048 + s2] = (__bf16)(acc[mi][ni][r] * rsm);
                }
            }
        }
        return;
    }
#pragma unroll
    for (int mi = 0; mi < 4; mi++) {
        int mbase = m0 + wrow + mi * 16 + 4 * g;
        f32x4 rv = {rs[mbase], rs[mbase + 1], rs[mbase + 2], rs[mbase + 3]};
#pragma unroll
        for (int ni = 0; ni < 4; ni++) {
            int n = n0 + wcol + ni * 16 + l;
#pragma unroll
            for (int r = 0; r < 4; r++) {
                float v = acc[mi][ni][r] * (rv[r] * wmv);
                if constexpr (MODE == 0) {
                    int m = mbase + r;
                    int b = m >> 11, s2 = m & 2047;
                    int h = n >> 6, hd = n & 63;
                    __bf16* dst = (z == 0) ? o0 : o1;
                    dst[(((size_t)(b * 16 + h)) * 2048 + s2) * 64 + hd] = (__bf16)v;
                } else {
                    outf[(size_t)(mbase + r) * 1024 + n] = v;
                }
            }
        }
    }
}

// ---------------- causal flash attention v4: swapped-operand QK^T / PV, lane-local softmax ----------------
// Work remap balances tile counts across XCDs and CU-resident block pairs:
//   t=(x+y)&15; xs = (y&16)? 15-t : t  ->  co-resident (lid, lid+256) get (t, 15-t): 34 tiles/CU const.
__global__ __launch_bounds__(512) void k_attn(const __bf16* __restrict__ qg, const __bf16* __restrict__ kb,
                                              const __bf16* __restrict__ vt, float* __restrict__ attn) {
    __shared__ __attribute__((aligned(16))) __bf16 Ks[3][4096];   // [key 64][d 64], 16B-chunk swizzled
    __shared__ __attribute__((aligned(16))) __bf16 Vs[3][4096];   // [hd 64][key 64], 16B-chunk swizzled
    int tid = threadIdx.x, w = tid >> 6, lane = tid & 63, g = lane >> 4, l = lane & 15;
    int bh = blockIdx.y, bq = bh >> 4, h = bh & 15;
    int xt = (blockIdx.x + blockIdx.y) & 15;
    int xs = (blockIdx.y & 16) ? (15 - xt) : xt;   // balanced slab index
    int q0 = xs * 128;
    size_t bhq = (size_t)bh * 2048 * 64;
    int qlo = q0 + w * 16, qmax = qlo + 15;
    int qrow = qlo + l;
    // Q fragments (B-operand: row = qrow(lane&15), k = 8g+j)
    bf16x8 aq0 = *(const bf16x8*)(qg + bhq + (size_t)qrow * 64 + 8 * g);
    bf16x8 aq1 = *(const bf16x8*)(qg + bhq + (size_t)qrow * 64 + 32 + 8 * g);
    asm volatile("" : "+v"(aq0), "+v"(aq1));   // pin Q in regs
    f32x4 o[4] = {};
    float mreg = -INFINITY, lsum = 0.f;
    // staging: wave w stages rows 8w..8w+7; linear LDS dest, inverse-swizzled global source
    int sRow = w * 8 + (lane >> 3);
    int sCol = ((lane & 7) ^ (lane >> 3)) << 3;
    const __bf16* Kg = kb + bhq + (size_t)sRow * 64 + sCol;
    const __bf16* Vg = vt + bhq + (size_t)sRow * 2048 + sCol;
    int nt = 2 * (xs + 1);
    // prologue: stage tiles 0,1
    gload16(Kg,        &Ks[0][w * 512]);
    gload16(Vg,        &Vs[0][w * 512]);
    gload16(Kg + 4096, &Ks[1][w * 512]);
    gload16(Vg + 64,   &Vs[1][w * 512]);
    int cur = 0;
    int swk = (l & 7) << 4;   // K-frag read swizzle (row kr: kr&7 == l&7)
    for (int t = 0; t < nt; ++t) {
        if (t < nt - 1) { asm volatile("s_waitcnt vmcnt(2)"); }
        else            { asm volatile("s_waitcnt vmcnt(0)"); }
        __builtin_amdgcn_s_barrier();
        __builtin_amdgcn_sched_barrier(0);
        int tn = t + 2;
        if (tn < nt) {
            int nbuf = cur + 2; if (nbuf >= 3) nbuf -= 3;
            gload16(Kg + (size_t)tn * 4096, &Ks[nbuf][w * 512]);
            gload16(Vg + tn * 64,           &Vs[nbuf][w * 512]);
        }
        int t0 = t * 64;
        if (t0 <= qmax) {
            const char* Kb = (const char*)&Ks[cur][0];
            const char* Vb = (const char*)&Vs[cur][0];
            // S^T = K.Q^T / 8: sv[nb] row=key(16nb+4g+r), col=qrow(l)
            f32x4 sv[4];
            __builtin_amdgcn_s_setprio(1);
#pragma unroll
            for (int nb = 0; nb < 4; nb++) {
                const char* kbase = Kb + (nb * 16 + l) * 128;
                bf16x8 bk0 = *(const bf16x8*)(kbase + ((16 * g) ^ swk));
                bf16x8 bk1 = *(const bf16x8*)(kbase + ((64 + 16 * g) ^ swk));
                f32x4 a = {};
                a = mfma16(bk0, aq0, a);   // swapped: A=K rows, B=Q rows
                a = mfma16(bk1, aq1, a);
                sv[nb] = a * 0.125f;
            }
            __builtin_amdgcn_s_setprio(0);
            if (t0 + 63 > qlo) {   // diagonal tile: causal mask (key > qrow)
#pragma unroll
                for (int nb = 0; nb < 4; nb++)
#pragma unroll
                    for (int r = 0; r < 4; r++) {
                        int key = t0 + nb * 16 + 4 * g + r;
                        if (key > qrow) sv[nb][r] = -INFINITY;
                    }
            }
            // lane-local row max over 16 held keys, then reduce over g (2 shuffles)
            float pm0 = fmaxf(fmaxf(sv[0][0], sv[0][1]), fmaxf(sv[0][2], sv[0][3]));
            float pm1 = fmaxf(fmaxf(sv[1][0], sv[1][1]), fmaxf(sv[1][2], sv[1][3]));
            float pm2 = fmaxf(fmaxf(sv[2][0], sv[2][1]), fmaxf(sv[2][2], sv[2][3]));
            float pm3 = fmaxf(fmaxf(sv[3][0], sv[3][1]), fmaxf(sv[3][2], sv[3][3]));
            float pm = fmaxf(fmaxf(pm0, pm1), fmaxf(pm2, pm3));
            pm = fmaxf(pm, __shfl_xor(pm, 16));
            pm = fmaxf(pm, __shfl_xor(pm, 32));
            float mnew = fmaxf(mreg, pm);
            float corr = __expf(mreg - mnew);
            mreg = mnew;
            // P = exp(S - m), row sum
            float psum = 0.f;
#pragma unroll
            for (int nb = 0; nb < 4; nb++)
#pragma unroll
                for (int r = 0; r < 4; r++) {
                    float pe = __expf(sv[nb][r] - mnew);
                    sv[nb][r] = pe;
                    psum += pe;
                }
            psum += __shfl_xor(psum, 16);
            psum += __shfl_xor(psum, 32);
            lsum = lsum * corr + psum;
#pragma unroll
            for (int hb = 0; hb < 4; hb++) o[hb] *= corr;
            // pack P into B-frags: slot (g,j) <-> key 32m + 16(j>>2) + 4g + (j&3)  (bijection)
            bf16x8 pf0, pf1;
#pragma unroll
            for (int j = 0; j < 8; j++) {
                pf0[j] = (__bf16)sv[j >> 2][j & 3];
                pf1[j] = (__bf16)sv[2 + (j >> 2)][j & 3];
            }
            // PV swapped: o[hb] row=hd(16hb+4g+r), col=qrow(l); V read in matching slot order
            __builtin_amdgcn_s_setprio(1);
#pragma unroll
            for (int hb = 0; hb < 4; hb++) {
                int vrow = hb * 16 + l;
                const char* vb = Vb + vrow * 128;
                int rsw = vrow & 7;          // == l&7
                int ib = 8 * (g & 1);
                int gh = g >> 1;
                bf16x4 v00 = *(const bf16x4*)(vb + 16 * ((gh + 0) ^ rsw) + ib);
                bf16x4 v01 = *(const bf16x4*)(vb + 16 * ((gh + 2) ^ rsw) + ib);
                bf16x8 vf0 = __builtin_shufflevector(v00, v01, 0, 1, 2, 3, 4, 5, 6, 7);
                o[hb] = mfma16(vf0, pf0, o[hb]);
                bf16x4 v10 = *(const bf16x4*)(vb + 16 * ((gh + 4) ^ rsw) + ib);
                bf16x4 v11 = *(const bf16x4*)(vb + 16 * ((gh + 6) ^ rsw) + ib);
                bf16x8 vf1 = __builtin_shufflevector(v10, v11, 0, 1, 2, 3, 4, 5, 6, 7);
                o[hb] = mfma16(vf1, pf1, o[hb]);
            }
            __builtin_amdgcn_s_setprio(0);
        }
        cur = (cur + 1 == 3) ? 0 : cur + 1;
    }
    // epilogue: lane (l,g) holds q = qlo+l, hd = 16hb+4g+r -> f32x4 stores
    float inv = 1.0f / lsum;
    float* dst = attn + ((size_t)(bq * 2048 + qlo + l)) * 1024 + h * 64 + 4 * g;
#pragma unroll
    for (int hb = 0; hb < 4; hb++) {
        f32x4 vsto = o[hb] * inv;
        *(f32x4*)(dst + 16 * hb) = vsto;
    }
}

extern "C" void kernel_launch(void* const* d_in, const int* in_sizes, int n_in,
                              void* d_out, int out_size, void* d_ws, size_t ws_size,
                              hipStream_t stream) {
    const float* x  = (const float*)d_in[0];
    // d_in[1] = mask: guaranteed causal tril, hardcoded in k_attn
    const float* Wq = (const float*)d_in[2];
    const float* Wk = (const float*)d_in[3];
    const float* Wv = (const float*)d_in[4];
    const float* Wo = (const float*)d_in[5];
    float* out = (float*)d_out;
    char* ws = (char*)d_ws;

    double* wsumd = (double*)(ws + 0);                       // 32 B
    float*  wmv   = (float*)(ws + 256);                      // 16 B
    __bf16* wqall = (__bf16*)(ws + 512);                     // 8 MB (4 x 1M bf16)
    __bf16* xq    = (__bf16*)(ws + 512 + 8388608);           // 8 MB
    float*  rsx   = (float*)(ws + 512 + 16777216);           // 16 KB
    float*  rso   = (float*)(ws + 512 + 16777216 + 16384);   // 16 KB
    char*   big   = ws + 512 + 16777216 + 32768;
    __bf16* qbuf  = (__bf16*)(big);                          // 8 MB
    __bf16* kbuf  = (__bf16*)(big + 8388608);                // 8 MB
    __bf16* oq    = (__bf16*)(big + 16777216);               // 8 MB
    __bf16* vtb   = (__bf16*)(big + 25165824);               // 8 MB (V^T, written by k_gemm z=2)
    float*  attn  = (float*)(big + 33554432);                // 16 MB

    hipMemsetAsync(ws, 0, 512, stream);
    k_wsum<<<dim3(256), 256, 0, stream>>>(Wq, Wk, Wv, Wo, wsumd);
    k_wquant<<<dim3(1024, 4), 256, 0, stream>>>(Wq, Wk, Wv, Wo, wsumd, wqall, wmv);
    k_actq<<<dim3(4096), 256, 0, stream>>>(x, xq, rsx);
    k_gemm<0><<<dim3(32, 8, 3), 256, 0, stream>>>(xq, wqall, rsx, wmv, qbuf, kbuf, vtb, nullptr);
    k_attn<<<dim3(16, 32), 512, 0, stream>>>(qbuf, kbuf, vtb, attn);
    k_actq<<<dim3(4096), 256, 0, stream>>>(attn, oq, rso);
    k_gemm<1><<<dim3(32, 8, 1), 256, 0, stream>>>(oq, wqall + 3 * 1048576, rso, wmv + 3,
                                                  nullptr, nullptr, nullptr, out);
}

// Round 7
// 240.739 us; speedup vs baseline: 1.3849x; 1.0089x over previous
//
#include <hip/hip_runtime.h>
#include <hip/hip_bf16.h>
#include <math.h>

// BitLinearAttention on gfx950.
// B=2, S=2048, D=1024, H=16, Hd=64, T=B*S=4096. All GEMMs done as exact-integer
// bf16 MFMA (qint in [-128,127], ternary weights), scales applied in epilogue.

typedef float  f32x4  __attribute__((ext_vector_type(4)));
typedef __bf16 bf16x8 __attribute__((ext_vector_type(8)));
typedef __bf16 bf16x4 __attribute__((ext_vector_type(4)));
typedef unsigned int u32x4 __attribute__((ext_vector_type(4)));

#define EPSV 1e-5f

__device__ __forceinline__ f32x4 mfma16(bf16x8 a, bf16x8 b, f32x4 c) {
    return __builtin_amdgcn_mfma_f32_16x16x32_bf16(a, b, c, 0, 0, 0);
}

__device__ __forceinline__ void gload16(const void* g, void* lds) {
    __builtin_amdgcn_global_load_lds((const __attribute__((address_space(1))) unsigned int*)g,
                                     (__attribute__((address_space(3))) unsigned int*)lds, 16, 0, 0);
}

// ---------------- weight |.| sum (fp64 accumulate) ----------------
__global__ __launch_bounds__(256) void k_wsum(const float* __restrict__ w0, const float* __restrict__ w1,
                                              const float* __restrict__ w2, const float* __restrict__ w3,
                                              double* __restrict__ wsum) {
    int w = blockIdx.x >> 6, chunk = blockIdx.x & 63, tid = threadIdx.x;
    const float* W = (w == 0) ? w0 : (w == 1) ? w1 : (w == 2) ? w2 : w3;
    const float* base = W + (size_t)chunk * 16384;
    float s = 0.f;
#pragma unroll
    for (int i = 0; i < 16; i++) {
        f32x4 v = *(const f32x4*)(base + i * 1024 + tid * 4);
        s += fabsf(v.x) + fabsf(v.y) + fabsf(v.z) + fabsf(v.w);
    }
#pragma unroll
    for (int off = 1; off < 64; off <<= 1) s += __shfl_xor(s, off);
    __shared__ float red[4];
    if ((tid & 63) == 0) red[tid >> 6] = s;
    __syncthreads();
    if (tid == 0) {
        double t = (double)red[0] + (double)red[1] + (double)red[2] + (double)red[3];
        atomicAdd(&wsum[w], t);
    }
}

// ---------------- ternary weight quantization ----------------
__global__ __launch_bounds__(256) void k_wquant(const float* __restrict__ w0, const float* __restrict__ w1,
                                                const float* __restrict__ w2, const float* __restrict__ w3,
                                                const double* __restrict__ wsum,
                                                __bf16* __restrict__ wq, float* __restrict__ wm) {
    int w = blockIdx.y;
    const float* W = (w == 0) ? w0 : (w == 1) ? w1 : (w == 2) ? w2 : w3;
    float mean = (float)(wsum[w] * (1.0 / 1048576.0));
    float ms = fmaxf(mean, EPSV);           // clip(mean, EPS)
    float scale = 1.0f / ms;
    int pos = blockIdx.x * 1024 + threadIdx.x * 4;
    f32x4 v = *(const f32x4*)(W + pos);
    float q0 = fminf(fmaxf(rintf(v.x * scale), -1.f), 1.f);
    float q1 = fminf(fmaxf(rintf(v.y * scale), -1.f), 1.f);
    float q2 = fminf(fmaxf(rintf(v.z * scale), -1.f), 1.f);
    float q3 = fminf(fmaxf(rintf(v.w * scale), -1.f), 1.f);
    unsigned int b0 = __builtin_bit_cast(unsigned short, (__bf16)q0);
    unsigned int b1 = __builtin_bit_cast(unsigned short, (__bf16)q1);
    unsigned int b2 = __builtin_bit_cast(unsigned short, (__bf16)q2);
    unsigned int b3 = __builtin_bit_cast(unsigned short, (__bf16)q3);
    uint2 p; p.x = b0 | (b1 << 16); p.y = b2 | (b3 << 16);
    *(uint2*)(wq + (size_t)w * 1048576 + pos) = p;
    if (blockIdx.x == 0 && threadIdx.x == 0) wm[w] = ms;   // weight multiplier = clip(mean|W|,EPS)
}

// ---------------- per-token int8 absmax act quant (stores integer values as bf16) ----------------
__global__ __launch_bounds__(256) void k_actq(const float* __restrict__ in, __bf16* __restrict__ outq,
                                              float* __restrict__ rs) {
    int t = blockIdx.x, tid = threadIdx.x;
    const float* row = in + (size_t)t * 1024;
    f32x4 v = *(const f32x4*)(row + tid * 4);
    float am = fmaxf(fmaxf(fabsf(v.x), fabsf(v.y)), fmaxf(fabsf(v.z), fabsf(v.w)));
#pragma unroll
    for (int off = 1; off < 64; off <<= 1) am = fmaxf(am, __shfl_xor(am, off));
    __shared__ float red[4];
    if ((tid & 63) == 0) red[tid >> 6] = am;
    __syncthreads();
    am = fmaxf(fmaxf(red[0], red[1]), fmaxf(red[2], red[3]));
    am = fmaxf(am, EPSV);                    // clip(absmax, EPS)
    float scale = 127.0f / am;
    float q0 = fminf(fmaxf(rintf(v.x * scale), -128.f), 127.f);
    float q1 = fminf(fmaxf(rintf(v.y * scale), -128.f), 127.f);
    float q2 = fminf(fmaxf(rintf(v.z * scale), -128.f), 127.f);
    float q3 = fminf(fmaxf(rintf(v.w * scale), -128.f), 127.f);
    unsigned int b0 = __builtin_bit_cast(unsigned short, (__bf16)q0);
    unsigned int b1 = __builtin_bit_cast(unsigned short, (__bf16)q1);
    unsigned int b2 = __builtin_bit_cast(unsigned short, (__bf16)q2);
    unsigned int b3 = __builtin_bit_cast(unsigned short, (__bf16)q3);
    uint2 p; p.x = b0 | (b1 << 16); p.y = b2 | (b3 << 16);
    *(uint2*)(outq + (size_t)t * 1024 + tid * 4) = p;
    if (tid == 0) rs[t] = am / 127.0f;       // 1/scale
}

// ---------------- GEMM: out[m][n] = sum_k X[m][k] * W[n][k], scaled by rs[m]*wm ----------------
// 3-stage pipelined (counted vmcnt, 1 barrier/step), XOR chunk-swizzled LDS (conflict-free b128).
// LDS physical chunk c of row r holds global k-chunk c ^ ((r>>1)&3); source pre-swizzled, dest linear.
// MODE 0: z=0/1 -> bf16 (b,h,s,hd) q/k; z=2 -> swapped operands, writes V^T (bh,hd,s) directly
// MODE 1: write fp32 into d_out (T x 1024)
template <int MODE>
__global__ __launch_bounds__(256) void k_gemm(const __bf16* __restrict__ X, const __bf16* __restrict__ Wb,
                                              const float* __restrict__ rs, const float* __restrict__ wm,
                                              __bf16* __restrict__ o0, __bf16* __restrict__ o1,
                                              __bf16* __restrict__ o2, float* __restrict__ outf) {
    __shared__ __attribute__((aligned(16))) __bf16 As[3][4096];
    __shared__ __attribute__((aligned(16))) __bf16 Bs[3][4096];
    int tid = threadIdx.x;
    int wave = tid >> 6, lane = tid & 63, g = lane >> 4, l = lane & 15;
    int m0 = blockIdx.x * 128, n0 = blockIdx.y * 128;
    int z = blockIdx.z;
    const __bf16* W = Wb + (size_t)z * 1048576;
    float wmv = wm[z];
    f32x4 acc[4][4] = {};
    // staging: lane -> row = wave*16 + (lane>>2) (+64 for inst 1), phys chunk = lane&3,
    // source k-chunk = (lane&3) ^ ((row>>1)&3) = (lane&3) ^ ((lane>>3)&3)   [64-row offset preserves it]
    int srow0 = wave * 16 + (lane >> 2);
    int scol = 8 * ((lane & 3) ^ ((lane >> 3) & 3));
    const __bf16* Ag = X + (size_t)(m0 + srow0) * 1024 + scol;
    const __bf16* Bg = W + (size_t)(n0 + srow0) * 1024 + scol;
    int woff = wave * 512;
    int wrow = (wave >> 1) * 64, wcol = (wave & 1) * 64;
    bool vswap = (MODE == 0) && (z == 2);
    const int NT = 32;   // K=1024 / BK=32
    // prologue: stage steps 0,1 into bufs 0,1 (4 gload16 each per wave)
#pragma unroll
    for (int s = 0; s < 2; s++) {
        gload16(Ag + s * 32,             &As[s][woff]);
        gload16(Ag + 64 * 1024 + s * 32, &As[s][woff + 2048]);
        gload16(Bg + s * 32,             &Bs[s][woff]);
        gload16(Bg + 64 * 1024 + s * 32, &Bs[s][woff + 2048]);
    }
    int cur = 0;
    int sel8 = 8 * (g ^ ((l >> 1) & 3));   // read-side swizzle: same for every fragment row block
    for (int t = 0; t < NT; ++t) {
        if (t < NT - 1) { asm volatile("s_waitcnt vmcnt(4)"); }
        else            { asm volatile("s_waitcnt vmcnt(0)"); }
        __builtin_amdgcn_s_barrier();
        __builtin_amdgcn_sched_barrier(0);
        int tn = t + 2;
        if (tn < NT) {   // stage t+2 into buf (cur+2)%3; that buf was read in step t-1 (barrier-safe)
            int nbuf = cur + 2; if (nbuf >= 3) nbuf -= 3;
            gload16(Ag + tn * 32,             &As[nbuf][woff]);
            gload16(Ag + 64 * 1024 + tn * 32, &As[nbuf][woff + 2048]);
            gload16(Bg + tn * 32,             &Bs[nbuf][woff]);
            gload16(Bg + 64 * 1024 + tn * 32, &Bs[nbuf][woff + 2048]);
        }
        bf16x8 af[4], bfr[4];
#pragma unroll
        for (int i = 0; i < 4; i++) af[i]  = *(const bf16x8*)&As[cur][(wrow + i * 16 + l) * 32 + sel8];
#pragma unroll
        for (int i = 0; i < 4; i++) bfr[i] = *(const bf16x8*)&Bs[cur][(wcol + i * 16 + l) * 32 + sel8];
        __builtin_amdgcn_s_setprio(1);
        if (vswap) {
#pragma unroll
            for (int mi = 0; mi < 4; mi++)
#pragma unroll
                for (int ni = 0; ni < 4; ni++)
                    acc[mi][ni] = mfma16(bfr[ni], af[mi], acc[mi][ni]);
        } else {
#pragma unroll
            for (int mi = 0; mi < 4; mi++)
#pragma unroll
                for (int ni = 0; ni < 4; ni++)
                    acc[mi][ni] = mfma16(af[mi], bfr[ni], acc[mi][ni]);
        }
        __builtin_amdgcn_s_setprio(0);
        cur = (cur + 1 == 3) ? 0 : cur + 1;
    }
    if (vswap) {
#pragma unroll
        for (int mi = 0; mi < 4; mi++) {
            int m = m0 + wrow + mi * 16 + l;
            float rsm = rs[m] * wmv;
            int b = m >> 11, s2 = m & 2047;
#pragma unroll
            for (int ni = 0; ni < 4; ni++) {
                int nb = n0 + wcol + ni * 16 + 4 * g;
#pragma unroll
                for (int r = 0; r < 4; r++) {
                    int n = nb + r;
                    int h = n >> 6, hd = n & 63;
                    o2[((size_t)(b * 16 + h) * 64 + hd) * 2048 + s2] = (__bf16)(acc[mi][ni][r] * rsm);
                }
            }
        }
        return;
    }
#pragma unroll
    for (int mi = 0; mi < 4; mi++) {
        int mbase = m0 + wrow + mi * 16 + 4 * g;
        f32x4 rv = {rs[mbase], rs[mbase + 1], rs[mbase + 2], rs[mbase + 3]};
#pragma unroll
        for (int ni = 0; ni < 4; ni++) {
            int n = n0 + wcol + ni * 16 + l;
#pragma unroll
            for (int r = 0; r < 4; r++) {
                float v = acc[mi][ni][r] * (rv[r] * wmv);
                if constexpr (MODE == 0) {
                    int m = mbase + r;
                    int b = m >> 11, s2 = m & 2047;
                    int h = n >> 6, hd = n & 63;
                    __bf16* dst = (z == 0) ? o0 : o1;
                    dst[(((size_t)(b * 16 + h)) * 2048 + s2) * 64 + hd] = (__bf16)v;
                } else {
                    outf[(size_t)(mbase + r) * 1024 + n] = v;
                }
            }
        }
    }
}

// ---------------- causal flash attention v4: swapped-operand QK^T / PV, lane-local softmax ----------------
// Work remap balances tile counts across XCDs and CU-resident block pairs:
//   t=(x+y)&15; xs = (y&16)? 15-t : t  ->  co-resident (lid, lid+256) get (t, 15-t): 34 tiles/CU const.
__global__ __launch_bounds__(512) void k_attn(const __bf16* __restrict__ qg, const __bf16* __restrict__ kb,
                                              const __bf16* __restrict__ vt, float* __restrict__ attn) {
    __shared__ __attribute__((aligned(16))) __bf16 Ks[3][4096];   // [key 64][d 64], 16B-chunk swizzled
    __shared__ __attribute__((aligned(16))) __bf16 Vs[3][4096];   // [hd 64][key 64], 16B-chunk swizzled
    int tid = threadIdx.x, w = tid >> 6, lane = tid & 63, g = lane >> 4, l = lane & 15;
    int bh = blockIdx.y, bq = bh >> 4, h = bh & 15;
    int xt = (blockIdx.x + blockIdx.y) & 15;
    int xs = (blockIdx.y & 16) ? (15 - xt) : xt;   // balanced slab index
    int q0 = xs * 128;
    size_t bhq = (size_t)bh * 2048 * 64;
    int qlo = q0 + w * 16, qmax = qlo + 15;
    int qrow = qlo + l;
    // Q fragments (B-operand: row = qrow(lane&15), k = 8g+j)
    bf16x8 aq0 = *(const bf16x8*)(qg + bhq + (size_t)qrow * 64 + 8 * g);
    bf16x8 aq1 = *(const bf16x8*)(qg + bhq + (size_t)qrow * 64 + 32 + 8 * g);
    asm volatile("" : "+v"(aq0), "+v"(aq1));   // pin Q in regs
    f32x4 o[4] = {};
    float mreg = -INFINITY, lsum = 0.f;
    // staging: wave w stages rows 8w..8w+7; linear LDS dest, inverse-swizzled global source
    int sRow = w * 8 + (lane >> 3);
    int sCol = ((lane & 7) ^ (lane >> 3)) << 3;
    const __bf16* Kg = kb + bhq + (size_t)sRow * 64 + sCol;
    const __bf16* Vg = vt + bhq + (size_t)sRow * 2048 + sCol;
    int nt = 2 * (xs + 1);
    // prologue: stage tiles 0,1
    gload16(Kg,        &Ks[0][w * 512]);
    gload16(Vg,        &Vs[0][w * 512]);
    gload16(Kg + 4096, &Ks[1][w * 512]);
    gload16(Vg + 64,   &Vs[1][w * 512]);
    int cur = 0;
    int swk = (l & 7) << 4;   // K-frag read swizzle (row kr: kr&7 == l&7)
    for (int t = 0; t < nt; ++t) {
        if (t < nt - 1) { asm volatile("s_waitcnt vmcnt(2)"); }
        else            { asm volatile("s_waitcnt vmcnt(0)"); }
        __builtin_amdgcn_s_barrier();
        __builtin_amdgcn_sched_barrier(0);
        int tn = t + 2;
        if (tn < nt) {
            int nbuf = cur + 2; if (nbuf >= 3) nbuf -= 3;
            gload16(Kg + (size_t)tn * 4096, &Ks[nbuf][w * 512]);
            gload16(Vg + tn * 64,           &Vs[nbuf][w * 512]);
        }
        int t0 = t * 64;
        if (t0 <= qmax) {
            const char* Kb = (const char*)&Ks[cur][0];
            const char* Vb = (const char*)&Vs[cur][0];
            // S^T = K.Q^T / 8: sv[nb] row=key(16nb+4g+r), col=qrow(l)
            f32x4 sv[4];
            __builtin_amdgcn_s_setprio(1);
#pragma unroll
            for (int nb = 0; nb < 4; nb++) {
                const char* kbase = Kb + (nb * 16 + l) * 128;
                bf16x8 bk0 = *(const bf16x8*)(kbase + ((16 * g) ^ swk));
                bf16x8 bk1 = *(const bf16x8*)(kbase + ((64 + 16 * g) ^ swk));
                f32x4 a = {};
                a = mfma16(bk0, aq0, a);   // swapped: A=K rows, B=Q rows
                a = mfma16(bk1, aq1, a);
                sv[nb] = a * 0.125f;
            }
            __builtin_amdgcn_s_setprio(0);
            if (t0 + 63 > qlo) {   // diagonal tile: causal mask (key > qrow)
#pragma unroll
                for (int nb = 0; nb < 4; nb++)
#pragma unroll
                    for (int r = 0; r < 4; r++) {
                        int key = t0 + nb * 16 + 4 * g + r;
                        if (key > qrow) sv[nb][r] = -INFINITY;
                    }
            }
            // lane-local row max over 16 held keys, then reduce over g (2 shuffles)
            float pm0 = fmaxf(fmaxf(sv[0][0], sv[0][1]), fmaxf(sv[0][2], sv[0][3]));
            float pm1 = fmaxf(fmaxf(sv[1][0], sv[1][1]), fmaxf(sv[1][2], sv[1][3]));
            float pm2 = fmaxf(fmaxf(sv[2][0], sv[2][1]), fmaxf(sv[2][2], sv[2][3]));
            float pm3 = fmaxf(fmaxf(sv[3][0], sv[3][1]), fmaxf(sv[3][2], sv[3][3]));
            float pm = fmaxf(fmaxf(pm0, pm1), fmaxf(pm2, pm3));
            pm = fmaxf(pm, __shfl_xor(pm, 16));
            pm = fmaxf(pm, __shfl_xor(pm, 32));
            float mnew = fmaxf(mreg, pm);
            float corr = __expf(mreg - mnew);
            mreg = mnew;
            // P = exp(S - m), row sum
            float psum = 0.f;
#pragma unroll
            for (int nb = 0; nb < 4; nb++)
#pragma unroll
                for (int r = 0; r < 4; r++) {
                    float pe = __expf(sv[nb][r] - mnew);
                    sv[nb][r] = pe;
                    psum += pe;
                }
            psum += __shfl_xor(psum, 16);
            psum += __shfl_xor(psum, 32);
            lsum = lsum * corr + psum;
#pragma unroll
            for (int hb = 0; hb < 4; hb++) o[hb] *= corr;
            // pack P into B-frags: slot (g,j) <-> key 32m + 16(j>>2) + 4g + (j&3)  (bijection)
            bf16x8 pf0, pf1;
#pragma unroll
            for (int j = 0; j < 8; j++) {
                pf0[j] = (__bf16)sv[j >> 2][j & 3];
                pf1[j] = (__bf16)sv[2 + (j >> 2)][j & 3];
            }
            // PV swapped: o[hb] row=hd(16hb+4g+r), col=qrow(l); V read in matching slot order
            __builtin_amdgcn_s_setprio(1);
#pragma unroll
            for (int hb = 0; hb < 4; hb++) {
                int vrow = hb * 16 + l;
                const char* vb = Vb + vrow * 128;
                int rsw = vrow & 7;          // == l&7
                int ib = 8 * (g & 1);
                int gh = g >> 1;
                bf16x4 v00 = *(const bf16x4*)(vb + 16 * ((gh + 0) ^ rsw) + ib);
                bf16x4 v01 = *(const bf16x4*)(vb + 16 * ((gh + 2) ^ rsw) + ib);
                bf16x8 vf0 = __builtin_shufflevector(v00, v01, 0, 1, 2, 3, 4, 5, 6, 7);
                o[hb] = mfma16(vf0, pf0, o[hb]);
                bf16x4 v10 = *(const bf16x4*)(vb + 16 * ((gh + 4) ^ rsw) + ib);
                bf16x4 v11 = *(const bf16x4*)(vb + 16 * ((gh + 6) ^ rsw) + ib);
                bf16x8 vf1 = __builtin_shufflevector(v10, v11, 0, 1, 2, 3, 4, 5, 6, 7);
                o[hb] = mfma16(vf1, pf1, o[hb]);
            }
            __builtin_amdgcn_s_setprio(0);
        }
        cur = (cur + 1 == 3) ? 0 : cur + 1;
    }
    // epilogue: lane (l,g) holds q = qlo+l, hd = 16hb+4g+r -> f32x4 stores
    float inv = 1.0f / lsum;
    float* dst = attn + ((size_t)(bq * 2048 + qlo + l)) * 1024 + h * 64 + 4 * g;
#pragma unroll
    for (int hb = 0; hb < 4; hb++) {
        f32x4 vsto = o[hb] * inv;
        *(f32x4*)(dst + 16 * hb) = vsto;
    }
}

extern "C" void kernel_launch(void* const* d_in, const int* in_sizes, int n_in,
                              void* d_out, int out_size, void* d_ws, size_t ws_size,
                              hipStream_t stream) {
    const float* x  = (const float*)d_in[0];
    // d_in[1] = mask: guaranteed causal tril, hardcoded in k_attn
    const float* Wq = (const float*)d_in[2];
    const float* Wk = (const float*)d_in[3];
    const float* Wv = (const float*)d_in[4];
    const float* Wo = (const float*)d_in[5];
    float* out = (float*)d_out;
    char* ws = (char*)d_ws;

    double* wsumd = (double*)(ws + 0);                       // 32 B
    float*  wmv   = (float*)(ws + 256);                      // 16 B
    __bf16* wqall = (__bf16*)(ws + 512);                     // 8 MB (4 x 1M bf16)
    __bf16* xq    = (__bf16*)(ws + 512 + 8388608);           // 8 MB
    float*  rsx   = (float*)(ws + 512 + 16777216);           // 16 KB
    float*  rso   = (float*)(ws + 512 + 16777216 + 16384);   // 16 KB
    char*   big   = ws + 512 + 16777216 + 32768;
    __bf16* qbuf  = (__bf16*)(big);                          // 8 MB
    __bf16* kbuf  = (__bf16*)(big + 8388608);                // 8 MB
    __bf16* oq    = (__bf16*)(big + 16777216);               // 8 MB
    __bf16* vtb   = (__bf16*)(big + 25165824);               // 8 MB (V^T, written by k_gemm z=2)
    float*  attn  = (float*)(big + 33554432);                // 16 MB

    hipMemsetAsync(ws, 0, 512, stream);
    k_wsum<<<dim3(256), 256, 0, stream>>>(Wq, Wk, Wv, Wo, wsumd);
    k_wquant<<<dim3(1024, 4), 256, 0, stream>>>(Wq, Wk, Wv, Wo, wsumd, wqall, wmv);
    k_actq<<<dim3(4096), 256, 0, stream>>>(x, xq, rsx);
    k_gemm<0><<<dim3(32, 8, 3), 256, 0, stream>>>(xq, wqall, rsx, wmv, qbuf, kbuf, vtb, nullptr);
    k_attn<<<dim3(16, 32), 512, 0, stream>>>(qbuf, kbuf, vtb, attn);
    k_actq<<<dim3(4096), 256, 0, stream>>>(attn, oq, rso);
    k_gemm<1><<<dim3(32, 8, 1), 256, 0, stream>>>(oq, wqall + 3 * 1048576, rso, wmv + 3,
                                                  nullptr, nullptr, nullptr, out);
}

// Round 9
// 229.125 us; speedup vs baseline: 1.4551x; 1.0507x over previous
//
#include <hip/hip_runtime.h>
#include <hip/hip_bf16.h>
#include <math.h>

// BitLinearAttention on gfx950.
// B=2, S=2048, D=1024, H=16, Hd=64, T=B*S=4096. All GEMMs done as exact-integer
// bf16 MFMA (qint in [-128,127], ternary weights), scales applied in epilogue.

typedef float  f32x4  __attribute__((ext_vector_type(4)));
typedef __bf16 bf16x8 __attribute__((ext_vector_type(8)));
typedef __bf16 bf16x4 __attribute__((ext_vector_type(4)));
typedef unsigned int u32x4 __attribute__((ext_vector_type(4)));

#define EPSV 1e-5f

__device__ __forceinline__ f32x4 mfma16(bf16x8 a, bf16x8 b, f32x4 c) {
    return __builtin_amdgcn_mfma_f32_16x16x32_bf16(a, b, c, 0, 0, 0);
}

__device__ __forceinline__ void gload16(const void* g, void* lds) {
    __builtin_amdgcn_global_load_lds((const __attribute__((address_space(1))) unsigned int*)g,
                                     (__attribute__((address_space(3))) unsigned int*)lds, 16, 0, 0);
}

// ---------------- weight |.| sum (fp64 accumulate) ----------------
__global__ __launch_bounds__(256) void k_wsum(const float* __restrict__ w0, const float* __restrict__ w1,
                                              const float* __restrict__ w2, const float* __restrict__ w3,
                                              double* __restrict__ wsum) {
    int w = blockIdx.x >> 6, chunk = blockIdx.x & 63, tid = threadIdx.x;
    const float* W = (w == 0) ? w0 : (w == 1) ? w1 : (w == 2) ? w2 : w3;
    const float* base = W + (size_t)chunk * 16384;
    float s = 0.f;
#pragma unroll
    for (int i = 0; i < 16; i++) {
        f32x4 v = *(const f32x4*)(base + i * 1024 + tid * 4);
        s += fabsf(v.x) + fabsf(v.y) + fabsf(v.z) + fabsf(v.w);
    }
#pragma unroll
    for (int off = 1; off < 64; off <<= 1) s += __shfl_xor(s, off);
    __shared__ float red[4];
    if ((tid & 63) == 0) red[tid >> 6] = s;
    __syncthreads();
    if (tid == 0) {
        double t = (double)red[0] + (double)red[1] + (double)red[2] + (double)red[3];
        atomicAdd(&wsum[w], t);
    }
}

// ---------------- ternary weight quantization ----------------
__global__ __launch_bounds__(256) void k_wquant(const float* __restrict__ w0, const float* __restrict__ w1,
                                                const float* __restrict__ w2, const float* __restrict__ w3,
                                                const double* __restrict__ wsum,
                                                __bf16* __restrict__ wq, float* __restrict__ wm) {
    int w = blockIdx.y;
    const float* W = (w == 0) ? w0 : (w == 1) ? w1 : (w == 2) ? w2 : w3;
    float mean = (float)(wsum[w] * (1.0 / 1048576.0));
    float ms = fmaxf(mean, EPSV);           // clip(mean, EPS)
    float scale = 1.0f / ms;
    int pos = blockIdx.x * 1024 + threadIdx.x * 4;
    f32x4 v = *(const f32x4*)(W + pos);
    float q0 = fminf(fmaxf(rintf(v.x * scale), -1.f), 1.f);
    float q1 = fminf(fmaxf(rintf(v.y * scale), -1.f), 1.f);
    float q2 = fminf(fmaxf(rintf(v.z * scale), -1.f), 1.f);
    float q3 = fminf(fmaxf(rintf(v.w * scale), -1.f), 1.f);
    unsigned int b0 = __builtin_bit_cast(unsigned short, (__bf16)q0);
    unsigned int b1 = __builtin_bit_cast(unsigned short, (__bf16)q1);
    unsigned int b2 = __builtin_bit_cast(unsigned short, (__bf16)q2);
    unsigned int b3 = __builtin_bit_cast(unsigned short, (__bf16)q3);
    uint2 p; p.x = b0 | (b1 << 16); p.y = b2 | (b3 << 16);
    *(uint2*)(wq + (size_t)w * 1048576 + pos) = p;
    if (blockIdx.x == 0 && threadIdx.x == 0) wm[w] = ms;   // weight multiplier = clip(mean|W|,EPS)
}

// ---------------- per-token int8 absmax act quant (stores integer values as bf16) ----------------
__global__ __launch_bounds__(256) void k_actq(const float* __restrict__ in, __bf16* __restrict__ outq,
                                              float* __restrict__ rs) {
    int t = blockIdx.x, tid = threadIdx.x;
    const float* row = in + (size_t)t * 1024;
    f32x4 v = *(const f32x4*)(row + tid * 4);
    float am = fmaxf(fmaxf(fabsf(v.x), fabsf(v.y)), fmaxf(fabsf(v.z), fabsf(v.w)));
#pragma unroll
    for (int off = 1; off < 64; off <<= 1) am = fmaxf(am, __shfl_xor(am, off));
    __shared__ float red[4];
    if ((tid & 63) == 0) red[tid >> 6] = am;
    __syncthreads();
    am = fmaxf(fmaxf(red[0], red[1]), fmaxf(red[2], red[3]));
    am = fmaxf(am, EPSV);                    // clip(absmax, EPS)
    float scale = 127.0f / am;
    float q0 = fminf(fmaxf(rintf(v.x * scale), -128.f), 127.f);
    float q1 = fminf(fmaxf(rintf(v.y * scale), -128.f), 127.f);
    float q2 = fminf(fmaxf(rintf(v.z * scale), -128.f), 127.f);
    float q3 = fminf(fmaxf(rintf(v.w * scale), -128.f), 127.f);
    unsigned int b0 = __builtin_bit_cast(unsigned short, (__bf16)q0);
    unsigned int b1 = __builtin_bit_cast(unsigned short, (__bf16)q1);
    unsigned int b2 = __builtin_bit_cast(unsigned short, (__bf16)q2);
    unsigned int b3 = __builtin_bit_cast(unsigned short, (__bf16)q3);
    uint2 p; p.x = b0 | (b1 << 16); p.y = b2 | (b3 << 16);
    *(uint2*)(outq + (size_t)t * 1024 + tid * 4) = p;
    if (tid == 0) rs[t] = am / 127.0f;       // 1/scale
}

// ---------------- GEMM v3: out[m][n] = sum_k X[m][k] * W[n][k], scaled by rs[m]*wm ----------------
// BK=64 (128B LDS rows), both-sides st-swizzle (16B chunk c of row r holds global chunk c^(r&7)),
// 2-buf 2-phase pipeline: STAGE(next) -> ds_read+MFMA(cur) -> __syncthreads (1 barrier/step, 16 steps).
// MODE 0: z=0/1 -> bf16 (b,h,s,hd) q/k; z=2 -> swapped operands, writes V^T (bh,hd,s) directly
// MODE 1: write fp32 into d_out (T x 1024)
template <int MODE>
__global__ __launch_bounds__(256) void k_gemm(const __bf16* __restrict__ X, const __bf16* __restrict__ Wb,
                                              const float* __restrict__ rs, const float* __restrict__ wm,
                                              __bf16* __restrict__ o0, __bf16* __restrict__ o1,
                                              __bf16* __restrict__ o2, float* __restrict__ outf) {
    __shared__ __attribute__((aligned(16))) __bf16 As[2][8192];   // [128][64] = 16KB per buf
    __shared__ __attribute__((aligned(16))) __bf16 Bs[2][8192];
    int tid = threadIdx.x;
    int wave = tid >> 6, lane = tid & 63, g = lane >> 4, l = lane & 15;
    int m0 = blockIdx.x * 128, n0 = blockIdx.y * 128;
    int z = blockIdx.z;
    const __bf16* W = Wb + (size_t)z * 1048576;
    float wmv = wm[z];
    f32x4 acc[4][4] = {};
    // staging: wave w, gload j (0..3), lane i -> dest row = w*32 + j*8 + (i>>3), phys chunk = i&7.
    // source global chunk = (i&7) ^ (row&7) = (i&7) ^ (i>>3): 8 lanes permute within one 128B row.
    int sRow = wave * 32 + (lane >> 3);
    int sCol = 8 * ((lane & 7) ^ (lane >> 3));
    const __bf16* Ag = X + (size_t)(m0 + sRow) * 1024 + sCol;
    const __bf16* Bg = W + (size_t)(n0 + sRow) * 1024 + sCol;
    int wrow = (wave >> 1) * 64, wcol = (wave & 1) * 64;
    bool vswap = (MODE == 0) && (z == 2);
    // prologue: stage step 0 into buf 0
#pragma unroll
    for (int j = 0; j < 4; j++) {
        gload16(Ag + (size_t)j * 8192, &As[0][(wave * 4 + j) * 512]);
        gload16(Bg + (size_t)j * 8192, &Bs[0][(wave * 4 + j) * 512]);
    }
    __syncthreads();
    for (int t = 0; t < 16; ++t) {
        int cur = t & 1;
        if (t < 15) {   // stage step t+1 into other buf; lands under this step's compute
            int nxt = cur ^ 1;
            int ko = (t + 1) * 64;
#pragma unroll
            for (int j = 0; j < 4; j++) {
                gload16(Ag + (size_t)j * 8192 + ko, &As[nxt][(wave * 4 + j) * 512]);
                gload16(Bg + (size_t)j * 8192 + ko, &Bs[nxt][(wave * 4 + j) * 512]);
            }
        }
        // fragment reads: row r = wrow/wcol + i*16 + l (r&7 == l&7); phys chunk = (4ks+g)^(l&7)
        bf16x8 af[4][2], bfr[4][2];
        int c0 = 8 * ((0 * 4 + g) ^ (l & 7));
        int c1 = 8 * ((1 * 4 + g) ^ (l & 7));
#pragma unroll
        for (int i = 0; i < 4; i++) {
            const __bf16* ra = &As[cur][(wrow + i * 16 + l) * 64];
            const __bf16* rb = &Bs[cur][(wcol + i * 16 + l) * 64];
            af[i][0]  = *(const bf16x8*)(ra + c0);
            af[i][1]  = *(const bf16x8*)(ra + c1);
            bfr[i][0] = *(const bf16x8*)(rb + c0);
            bfr[i][1] = *(const bf16x8*)(rb + c1);
        }
        __builtin_amdgcn_s_setprio(1);
#pragma unroll
        for (int ks = 0; ks < 2; ks++) {
            if (vswap) {
#pragma unroll
                for (int mi = 0; mi < 4; mi++)
#pragma unroll
                    for (int ni = 0; ni < 4; ni++)
                        acc[mi][ni] = mfma16(bfr[ni][ks], af[mi][ks], acc[mi][ni]);
            } else {
#pragma unroll
                for (int mi = 0; mi < 4; mi++)
#pragma unroll
                    for (int ni = 0; ni < 4; ni++)
                        acc[mi][ni] = mfma16(af[mi][ks], bfr[ni][ks], acc[mi][ni]);
            }
        }
        __builtin_amdgcn_s_setprio(0);
        __syncthreads();   // drains vmcnt(0): next buf landed; all waves done reading cur
    }
    if (vswap) {
#pragma unroll
        for (int mi = 0; mi < 4; mi++) {
            int m = m0 + wrow + mi * 16 + l;
            float rsm = rs[m] * wmv;
            int b = m >> 11, s2 = m & 2047;
#pragma unroll
            for (int ni = 0; ni < 4; ni++) {
                int nb = n0 + wcol + ni * 16 + 4 * g;
#pragma unroll
                for (int r = 0; r < 4; r++) {
                    int n = nb + r;
                    int h = n >> 6, hd = n & 63;
                    o2[((size_t)(b * 16 + h) * 64 + hd) * 2048 + s2] = (__bf16)(acc[mi][ni][r] * rsm);
                }
            }
        }
        return;
    }
#pragma unroll
    for (int mi = 0; mi < 4; mi++) {
        int mbase = m0 + wrow + mi * 16 + 4 * g;
        f32x4 rv = {rs[mbase], rs[mbase + 1], rs[mbase + 2], rs[mbase + 3]};
#pragma unroll
        for (int ni = 0; ni < 4; ni++) {
            int n = n0 + wcol + ni * 16 + l;
#pragma unroll
            for (int r = 0; r < 4; r++) {
                float v = acc[mi][ni][r] * (rv[r] * wmv);
                if constexpr (MODE == 0) {
                    int m = mbase + r;
                    int b = m >> 11, s2 = m & 2047;
                    int h = n >> 6, hd = n & 63;
                    __bf16* dst = (z == 0) ? o0 : o1;
                    dst[(((size_t)(b * 16 + h)) * 2048 + s2) * 64 + hd] = (__bf16)v;
                } else {
                    outf[(size_t)(mbase + r) * 1024 + n] = v;
                }
            }
        }
    }
}

// ---------------- causal flash attention v5: XCD-affine work map + swapped-operand MFMA ----------------
// bh = (x&7)|((y&3)<<3): all 16 q-slabs of a head run on ONE XCD (XCD = lid&7 = x&7) -> K/V L2-resident
// (4 heads x 512KB = 2MB per XCD L2). Slab index from (u=x>>3, v=y>>2), co-resident pair (y, y+16)
// shares bh and gets balanced lengths (xs, 15-xs).
__global__ __launch_bounds__(512) void k_attn(const __bf16* __restrict__ qg, const __bf16* __restrict__ kb,
                                              const __bf16* __restrict__ vt, float* __restrict__ attn) {
    __shared__ __attribute__((aligned(16))) __bf16 Ks[3][4096];   // [key 64][d 64], 16B-chunk swizzled
    __shared__ __attribute__((aligned(16))) __bf16 Vs[3][4096];   // [hd 64][key 64], 16B-chunk swizzled
    int tid = threadIdx.x, w = tid >> 6, lane = tid & 63, g = lane >> 4, l = lane & 15;
    int bx = blockIdx.x, by = blockIdx.y;
    int bh = (bx & 7) | ((by & 3) << 3);
    int u = bx >> 3, v = by >> 2;
    int base2 = 2 * ((u << 2) | (v & 3));
    int xs = (v < 4) ? base2 : 15 - base2;         // balanced + XCD-affine slab index
    int bq = bh >> 4, h = bh & 15;
    int q0 = xs * 128;
    size_t bhq = (size_t)bh * 2048 * 64;
    int qlo = q0 + w * 16, qmax = qlo + 15;
    int qrow = qlo + l;
    // Q fragments (B-operand: row = qrow(lane&15), k = 8g+j)
    bf16x8 aq0 = *(const bf16x8*)(qg + bhq + (size_t)qrow * 64 + 8 * g);
    bf16x8 aq1 = *(const bf16x8*)(qg + bhq + (size_t)qrow * 64 + 32 + 8 * g);
    asm volatile("" : "+v"(aq0), "+v"(aq1));   // pin Q in regs
    f32x4 o[4] = {};
    float mreg = -INFINITY, lsum = 0.f;
    // staging: wave w stages rows 8w..8w+7; linear LDS dest, inverse-swizzled global source
    int sRow = w * 8 + (lane >> 3);
    int sCol = ((lane & 7) ^ (lane >> 3)) << 3;
    const __bf16* Kg = kb + bhq + (size_t)sRow * 64 + sCol;
    const __bf16* Vg = vt + bhq + (size_t)sRow * 2048 + sCol;
    int nt = 2 * (xs + 1);
    // prologue: stage tiles 0,1
    gload16(Kg,        &Ks[0][w * 512]);
    gload16(Vg,        &Vs[0][w * 512]);
    gload16(Kg + 4096, &Ks[1][w * 512]);
    gload16(Vg + 64,   &Vs[1][w * 512]);
    int cur = 0;
    int swk = (l & 7) << 4;   // K-frag read swizzle (row kr: kr&7 == l&7)
    for (int t = 0; t < nt; ++t) {
        if (t < nt - 1) { asm volatile("s_waitcnt vmcnt(2)"); }
        else            { asm volatile("s_waitcnt vmcnt(0)"); }
        __builtin_amdgcn_s_barrier();
        __builtin_amdgcn_sched_barrier(0);
        int tn = t + 2;
        if (tn < nt) {
            int nbuf = cur + 2; if (nbuf >= 3) nbuf -= 3;
            gload16(Kg + (size_t)tn * 4096, &Ks[nbuf][w * 512]);
            gload16(Vg + tn * 64,           &Vs[nbuf][w * 512]);
        }
        int t0 = t * 64;
        if (t0 <= qmax) {
            const char* Kb = (const char*)&Ks[cur][0];
            const char* Vb = (const char*)&Vs[cur][0];
            // S^T = K.Q^T / 8: sv[nb] row=key(16nb+4g+r), col=qrow(l)
            f32x4 sv[4];
            __builtin_amdgcn_s_setprio(1);
#pragma unroll
            for (int nb = 0; nb < 4; nb++) {
                const char* kbase = Kb + (nb * 16 + l) * 128;
                bf16x8 bk0 = *(const bf16x8*)(kbase + ((16 * g) ^ swk));
                bf16x8 bk1 = *(const bf16x8*)(kbase + ((64 + 16 * g) ^ swk));
                f32x4 a = {};
                a = mfma16(bk0, aq0, a);   // swapped: A=K rows, B=Q rows
                a = mfma16(bk1, aq1, a);
                sv[nb] = a * 0.125f;
            }
            __builtin_amdgcn_s_setprio(0);
            if (t0 + 63 > qlo) {   // diagonal tile: causal mask (key > qrow)
#pragma unroll
                for (int nb = 0; nb < 4; nb++)
#pragma unroll
                    for (int r = 0; r < 4; r++) {
                        int key = t0 + nb * 16 + 4 * g + r;
                        if (key > qrow) sv[nb][r] = -INFINITY;
                    }
            }
            // lane-local row max over 16 held keys, then reduce over g (2 shuffles)
            float pm0 = fmaxf(fmaxf(sv[0][0], sv[0][1]), fmaxf(sv[0][2], sv[0][3]));
            float pm1 = fmaxf(fmaxf(sv[1][0], sv[1][1]), fmaxf(sv[1][2], sv[1][3]));
            float pm2 = fmaxf(fmaxf(sv[2][0], sv[2][1]), fmaxf(sv[2][2], sv[2][3]));
            float pm3 = fmaxf(fmaxf(sv[3][0], sv[3][1]), fmaxf(sv[3][2], sv[3][3]));
            float pm = fmaxf(fmaxf(pm0, pm1), fmaxf(pm2, pm3));
            pm = fmaxf(pm, __shfl_xor(pm, 16));
            pm = fmaxf(pm, __shfl_xor(pm, 32));
            float mnew = fmaxf(mreg, pm);
            float corr = __expf(mreg - mnew);
            mreg = mnew;
            // P = exp(S - m), row sum
            float psum = 0.f;
#pragma unroll
            for (int nb = 0; nb < 4; nb++)
#pragma unroll
                for (int r = 0; r < 4; r++) {
                    float pe = __expf(sv[nb][r] - mnew);
                    sv[nb][r] = pe;
                    psum += pe;
                }
            psum += __shfl_xor(psum, 16);
            psum += __shfl_xor(psum, 32);
            lsum = lsum * corr + psum;
#pragma unroll
            for (int hb = 0; hb < 4; hb++) o[hb] *= corr;
            // pack P into B-frags: slot (g,j) <-> key 32m + 16(j>>2) + 4g + (j&3)  (bijection)
            bf16x8 pf0, pf1;
#pragma unroll
            for (int j = 0; j < 8; j++) {
                pf0[j] = (__bf16)sv[j >> 2][j & 3];
                pf1[j] = (__bf16)sv[2 + (j >> 2)][j & 3];
            }
            // PV swapped: o[hb] row=hd(16hb+4g+r), col=qrow(l); V read in matching slot order
            __builtin_amdgcn_s_setprio(1);
#pragma unroll
            for (int hb = 0; hb < 4; hb++) {
                int vrow = hb * 16 + l;
                const char* vb = Vb + vrow * 128;
                int rsw = vrow & 7;          // == l&7
                int ib = 8 * (g & 1);
                int gh = g >> 1;
                bf16x4 v00 = *(const bf16x4*)(vb + 16 * ((gh + 0) ^ rsw) + ib);
                bf16x4 v01 = *(const bf16x4*)(vb + 16 * ((gh + 2) ^ rsw) + ib);
                bf16x8 vf0 = __builtin_shufflevector(v00, v01, 0, 1, 2, 3, 4, 5, 6, 7);
                o[hb] = mfma16(vf0, pf0, o[hb]);
                bf16x4 v10 = *(const bf16x4*)(vb + 16 * ((gh + 4) ^ rsw) + ib);
                bf16x4 v11 = *(const bf16x4*)(vb + 16 * ((gh + 6) ^ rsw) + ib);
                bf16x8 vf1 = __builtin_shufflevector(v10, v11, 0, 1, 2, 3, 4, 5, 6, 7);
                o[hb] = mfma16(vf1, pf1, o[hb]);
            }
            __builtin_amdgcn_s_setprio(0);
        }
        cur = (cur + 1 == 3) ? 0 : cur + 1;
    }
    // epilogue: lane (l,g) holds q = qlo+l, hd = 16hb+4g+r -> f32x4 stores
    float inv = 1.0f / lsum;
    float* dst = attn + ((size_t)(bq * 2048 + qlo + l)) * 1024 + h * 64 + 4 * g;
#pragma unroll
    for (int hb = 0; hb < 4; hb++) {
        f32x4 vsto = o[hb] * inv;
        *(f32x4*)(dst + 16 * hb) = vsto;
    }
}

extern "C" void kernel_launch(void* const* d_in, const int* in_sizes, int n_in,
                              void* d_out, int out_size, void* d_ws, size_t ws_size,
                              hipStream_t stream) {
    const float* x  = (const float*)d_in[0];
    // d_in[1] = mask: guaranteed causal tril, hardcoded in k_attn
    const float* Wq = (const float*)d_in[2];
    const float* Wk = (const float*)d_in[3];
    const float* Wv = (const float*)d_in[4];
    const float* Wo = (const float*)d_in[5];
    float* out = (float*)d_out;
    char* ws = (char*)d_ws;

    double* wsumd = (double*)(ws + 0);                       // 32 B
    float*  wmv   = (float*)(ws + 256);                      // 16 B
    __bf16* wqall = (__bf16*)(ws + 512);                     // 8 MB (4 x 1M bf16)
    __bf16* xq    = (__bf16*)(ws + 512 + 8388608);           // 8 MB
    float*  rsx   = (float*)(ws + 512 + 16777216);           // 16 KB
    float*  rso   = (float*)(ws + 512 + 16777216 + 16384);   // 16 KB
    char*   big   = ws + 512 + 16777216 + 32768;
    __bf16* qbuf  = (__bf16*)(big);                          // 8 MB
    __bf16* kbuf  = (__bf16*)(big + 8388608);                // 8 MB
    __bf16* oq    = (__bf16*)(big + 16777216);               // 8 MB
    __bf16* vtb   = (__bf16*)(big + 25165824);               // 8 MB (V^T, written by k_gemm z=2)
    float*  attn  = (float*)(big + 33554432);                // 16 MB

    hipMemsetAsync(ws, 0, 512, stream);
    k_wsum<<<dim3(256), 256, 0, stream>>>(Wq, Wk, Wv, Wo, wsumd);
    k_wquant<<<dim3(1024, 4), 256, 0, stream>>>(Wq, Wk, Wv, Wo, wsumd, wqall, wmv);
    k_actq<<<dim3(4096), 256, 0, stream>>>(x, xq, rsx);
    k_gemm<0><<<dim3(32, 8, 3), 256, 0, stream>>>(xq, wqall, rsx, wmv, qbuf, kbuf, vtb, nullptr);
    k_attn<<<dim3(16, 32), 512, 0, stream>>>(qbuf, kbuf, vtb, attn);
    k_actq<<<dim3(4096), 256, 0, stream>>>(attn, oq, rso);
    k_gemm<1><<<dim3(32, 8, 1), 256, 0, stream>>>(oq, wqall + 3 * 1048576, rso, wmv + 3,
                                                  nullptr, nullptr, nullptr, out);
}